// Round 13
// baseline (303.752 us; speedup 1.0000x reference)
//
#include <hip/hip_runtime.h>
#include <hip/hip_fp16.h>
#include <type_traits>

#define NEG_SLOPE 0.2f
#define INV_SQRT2 0.7071067811865476f
#define BCAP 8192   // padded per-bucket staging capacity (avg ~4337 edges/bucket)
#define NPART 32    // bn_part grid (partials reduced inline by consumer GEMMs)

typedef _Float16 half8 __attribute__((ext_vector_type(8)));
typedef float floatx4 __attribute__((ext_vector_type(4)));

__device__ __forceinline__ float lrelu(float x) { return x > 0.f ? x : NEG_SLOPE * x; }

// ---------------- weight prep + bfill zero ----------------

__global__ __launch_bounds__(256) void prep_weights(const float* __restrict__ W1,
                                                    const float* __restrict__ W2,
                                                    const float* __restrict__ Wres,
                                                    const float* __restrict__ Wfin,
                                                    _Float16* __restrict__ W1t,
                                                    _Float16* __restrict__ W2t,
                                                    _Float16* __restrict__ Wrt,
                                                    _Float16* __restrict__ Wft,
                                                    int* __restrict__ bfill) {
    if (blockIdx.x == 0) bfill[threadIdx.x] = 0;
    int i = blockIdx.x * 256 + threadIdx.x;
    if (i < 16384) {
        int k = i >> 7, n = i & 127;
        W1t[n * 136 + k] = (_Float16)W1[i];
    } else if (i < 32768) {
        int j = i - 16384; int k = j >> 7, n = j & 127;
        W2t[n * 136 + k] = (_Float16)W2[j];
    } else if (i < 49152) {
        int j = i - 32768; int k = j >> 7, n = j & 127;
        Wrt[n * 136 + k] = (_Float16)Wres[j];
    } else if (i < 53248) {
        int j = i - 49152; int k = j >> 5, n = j & 31;
        Wft[n * 136 + k] = (_Float16)Wfin[j];
    }
}

// ---------------- CSR build: two-level bucket sort by dst ----------------
// staging entry packed: src (24 bits) | (dst & 255) << 24

__device__ void scatter_body(const int* __restrict__ src, const int* __restrict__ dst,
                             int* __restrict__ bucket_fill, unsigned* __restrict__ staging,
                             int E, int N, int chunk) {
    __shared__ int lds[256];
    int tid = threadIdx.x;
    int M = E + N;
    int begin = blockIdx.x * chunk;
    int endc = min(begin + chunk, M);
    lds[tid] = 0;
    __syncthreads();
    for (int i = begin + tid; i < endc; i += 256) {
        int d = (i < E) ? dst[i] : (i - E);
        atomicAdd(&lds[d >> 8], 1);
    }
    __syncthreads();
    int h = lds[tid];
    int base = 0;
    if (h > 0) base = atomicAdd(&bucket_fill[tid], h);
    __syncthreads();
    lds[tid] = base;
    __syncthreads();
    for (int i = begin + tid; i < endc; i += 256) {
        int s, d;
        if (i < E) { s = src[i]; d = dst[i]; } else { s = d = i - E; }
        int b = d >> 8;
        int r = atomicAdd(&lds[b], 1);
        if (r < BCAP) staging[b * BCAP + r] = (unsigned)s | ((unsigned)(d & 255) << 24);
    }
}

__global__ __launch_bounds__(256) void fine_sort(const unsigned* __restrict__ staging,
                                                 const int* __restrict__ bucket_fill,
                                                 int* __restrict__ row_ptr,
                                                 int* __restrict__ csr_src, int NB, int N) {
    __shared__ int sb[256];
    __shared__ int c1[256];
    __shared__ int s1[256];
    int t = threadIdx.x;
    int b = blockIdx.x;
    int c = (t < NB) ? min(bucket_fill[t], BCAP) : 0;
    sb[t] = c;
    __syncthreads();
    for (int off = 1; off < 256; off <<= 1) {
        int add = (t >= off) ? sb[t - off] : 0;
        __syncthreads();
        sb[t] += add;
        __syncthreads();
    }
    int hi = sb[b];
    int lo = (b > 0) ? sb[b - 1] : 0;
    int cnt = hi - lo;
    if (b == NB - 1 && t == 0) row_ptr[N] = sb[NB - 1];
    const unsigned* stg = staging + (long)b * BCAP;
    c1[t] = 0;
    __syncthreads();
    for (int k = t; k < cnt; k += 256) atomicAdd(&c1[stg[k] >> 24], 1);
    __syncthreads();
    int v = c1[t];
    s1[t] = v;
    __syncthreads();
    for (int off = 1; off < 256; off <<= 1) {
        int add = (t >= off) ? s1[t - off] : 0;
        __syncthreads();
        s1[t] += add;
        __syncthreads();
    }
    int excl = s1[t] - v;
    int node = b * 256 + t;
    if (node < N) row_ptr[node] = lo + excl;
    c1[t] = lo + excl;   // cursor
    __syncthreads();
    for (int k = t; k < cnt; k += 256) {
        unsigned e = stg[k];
        int p = atomicAdd(&c1[e >> 24], 1);
        csr_src[p] = (int)(e & 0xFFFFFFu);
    }
}

// ---------------- MFMA f16 GEMM body (device fn) ----------------
// A-layout (verified): lane supplies A[m = lane&15][k = quad*8 + j]. W staged in LDS.
// DO_BN: scale/shift computed inline from NPART bn partials (threads 0..127, LDS).
// ATTN = 0/1/4: as/ad from fp32 accumulators, shfl over the 16-lane quad-group.

template <int NCOLS, bool DO_BN, int ATTN, typename AT>
__device__ void gemm_body(int bid, const AT* __restrict__ A, const _Float16* __restrict__ Wt,
                          const float* __restrict__ bnpart, const float* __restrict__ gamma,
                          const float* __restrict__ beta, float invN,
                          const float* __restrict__ a_src, const float* __restrict__ a_dst,
                          float* __restrict__ as_out, float* __restrict__ ad_out,
                          _Float16* __restrict__ out_h, int nrows) {
    __shared__ __align__(16) _Float16 Ws[NCOLS * 136];
    __shared__ __align__(16) float bnsc[DO_BN ? 128 : 4];
    __shared__ __align__(16) float bnsh[DO_BN ? 128 : 4];
    int tid = threadIdx.x;
    {
        const float4* srcp = (const float4*)Wt;
        float4* dstp = (float4*)Ws;
        for (int i = tid; i < NCOLS * 17; i += 256) dstp[i] = srcp[i];
    }
    if (DO_BN && tid < 128) {
        float s = 0.f, q = 0.f;
#pragma unroll 8
        for (int k = 0; k < NPART; ++k) {
            s += bnpart[k * 256 + tid];
            q += bnpart[k * 256 + 128 + tid];
        }
        float mean = s * invN;
        float var = q * invN - mean * mean;
        float sc = gamma[tid] * rsqrtf(var + 1e-5f);
        bnsc[tid] = sc;
        bnsh[tid] = beta[tid] - mean * sc;
    }
    __syncthreads();

    int wave = tid >> 6, lane = tid & 63;
    int lrow = lane & 15, quad = lane >> 4;
    int m0 = bid * 128 + wave * 32;
    long r0 = min(m0 + lrow, nrows - 1);
    long r1 = min(m0 + 16 + lrow, nrows - 1);
    constexpr int NT = NCOLS / 16;
    floatx4 acc[2][NT];
#pragma unroll
    for (int ms = 0; ms < 2; ++ms)
#pragma unroll
        for (int nt = 0; nt < NT; ++nt) acc[ms][nt] = (floatx4){0.f, 0.f, 0.f, 0.f};

#pragma unroll
    for (int ks = 0; ks < 4; ++ks) {
        int k0 = ks * 32 + quad * 8;
        float av[2][8];
        if constexpr (std::is_same<AT, float>::value) {
            float4 f0 = *(const float4*)&A[r0 * 128 + k0];
            float4 f1 = *(const float4*)&A[r0 * 128 + k0 + 4];
            av[0][0] = f0.x; av[0][1] = f0.y; av[0][2] = f0.z; av[0][3] = f0.w;
            av[0][4] = f1.x; av[0][5] = f1.y; av[0][6] = f1.z; av[0][7] = f1.w;
            float4 g0 = *(const float4*)&A[r1 * 128 + k0];
            float4 g1 = *(const float4*)&A[r1 * 128 + k0 + 4];
            av[1][0] = g0.x; av[1][1] = g0.y; av[1][2] = g0.z; av[1][3] = g0.w;
            av[1][4] = g1.x; av[1][5] = g1.y; av[1][6] = g1.z; av[1][7] = g1.w;
        } else {
            half8 h0 = *(const half8*)&A[r0 * 128 + k0];
            half8 h1 = *(const half8*)&A[r1 * 128 + k0];
#pragma unroll
            for (int u = 0; u < 8; ++u) {
                av[0][u] = (float)h0[u];
                av[1][u] = (float)h1[u];
            }
        }
        if (DO_BN) {
            float4 sc0 = *(const float4*)&bnsc[k0];
            float4 sc1 = *(const float4*)&bnsc[k0 + 4];
            float4 sh0 = *(const float4*)&bnsh[k0];
            float4 sh1 = *(const float4*)&bnsh[k0 + 4];
            float scv[8] = {sc0.x, sc0.y, sc0.z, sc0.w, sc1.x, sc1.y, sc1.z, sc1.w};
            float shv[8] = {sh0.x, sh0.y, sh0.z, sh0.w, sh1.x, sh1.y, sh1.z, sh1.w};
#pragma unroll
            for (int ms = 0; ms < 2; ++ms)
#pragma unroll
                for (int u = 0; u < 8; ++u)
                    av[ms][u] = fmaxf(av[ms][u] * scv[u] + shv[u], 0.f);
        }
        half8 a0h, a1h;
#pragma unroll
        for (int u = 0; u < 8; ++u) {
            a0h[u] = (_Float16)av[0][u];
            a1h[u] = (_Float16)av[1][u];
        }
#pragma unroll
        for (int nt = 0; nt < NT; ++nt) {
            half8 b = *(half8*)&Ws[(nt * 16 + lrow) * 136 + k0];
            acc[0][nt] = __builtin_amdgcn_mfma_f32_16x16x32_f16(a0h, b, acc[0][nt], 0, 0, 0);
            acc[1][nt] = __builtin_amdgcn_mfma_f32_16x16x32_f16(a1h, b, acc[1][nt], 0, 0, 0);
        }
    }

    // epilogue: C/D layout col=lane&15, row=quad*4+reg
#pragma unroll
    for (int ms = 0; ms < 2; ++ms) {
#pragma unroll
        for (int nt = 0; nt < NT; ++nt) {
            int col = nt * 16 + lrow;
#pragma unroll
            for (int reg = 0; reg < 4; ++reg) {
                int r = m0 + ms * 16 + quad * 4 + reg;
                if (r < nrows) out_h[(long)r * NCOLS + col] = (_Float16)acc[ms][nt][reg];
            }
        }
    }

    if constexpr (ATTN > 0) {
        float asrc_l[NT], adst_l[NT];
#pragma unroll
        for (int nt = 0; nt < NT; ++nt) {
            asrc_l[nt] = a_src[nt * 16 + lrow];
            adst_l[nt] = a_dst[nt * 16 + lrow];
        }
#pragma unroll
        for (int ms = 0; ms < 2; ++ms) {
#pragma unroll
            for (int reg = 0; reg < 4; ++reg) {
                int r = m0 + ms * 16 + quad * 4 + reg;
                if constexpr (ATTN == 4) {
                    float ps[4], pd[4];
#pragma unroll
                    for (int h = 0; h < 4; ++h) {
                        ps[h] = acc[ms][2 * h][reg] * asrc_l[2 * h] +
                                acc[ms][2 * h + 1][reg] * asrc_l[2 * h + 1];
                        pd[h] = acc[ms][2 * h][reg] * adst_l[2 * h] +
                                acc[ms][2 * h + 1][reg] * adst_l[2 * h + 1];
                    }
#pragma unroll
                    for (int off = 1; off < 16; off <<= 1) {
#pragma unroll
                        for (int h = 0; h < 4; ++h) {
                            ps[h] += __shfl_xor(ps[h], off);
                            pd[h] += __shfl_xor(pd[h], off);
                        }
                    }
                    if (r < nrows && lrow < 4) {
                        float psv = lrow == 0 ? ps[0] : lrow == 1 ? ps[1]
                                  : lrow == 2 ? ps[2] : ps[3];
                        float pdv = lrow == 0 ? pd[0] : lrow == 1 ? pd[1]
                                  : lrow == 2 ? pd[2] : pd[3];
                        as_out[r * 4 + lrow] = psv;
                        ad_out[r * 4 + lrow] = pdv;
                    }
                } else {
                    float ps = 0.f, pd = 0.f;
#pragma unroll
                    for (int nt = 0; nt < NT; ++nt) {
                        ps += acc[ms][nt][reg] * asrc_l[nt];
                        pd += acc[ms][nt][reg] * adst_l[nt];
                    }
#pragma unroll
                    for (int off = 1; off < 16; off <<= 1) {
                        ps += __shfl_xor(ps, off);
                        pd += __shfl_xor(pd, off);
                    }
                    if (r < nrows && lrow == 0) {
                        as_out[r] = ps;
                        ad_out[r] = pd;
                    }
                }
            }
        }
    }
}

// ---------------- fused bucket_scatter + conv1 (independent work, one dispatch) ----------------

__global__ __launch_bounds__(256) void scatter_conv1(const int* __restrict__ src,
                                                     const int* __restrict__ dst,
                                                     int* __restrict__ bucket_fill,
                                                     unsigned* __restrict__ staging,
                                                     int E, int Nn, int chunk, int scat_blks,
                                                     const float* __restrict__ x,
                                                     const _Float16* __restrict__ W1t,
                                                     const float* __restrict__ a_src,
                                                     const float* __restrict__ a_dst,
                                                     float* __restrict__ as_out,
                                                     float* __restrict__ ad_out,
                                                     _Float16* __restrict__ out_h, int nrows) {
    if ((int)blockIdx.x < scat_blks) {
        scatter_body(src, dst, bucket_fill, staging, E, Nn, chunk);
    } else {
        gemm_body<128, false, 4, float>(blockIdx.x - scat_blks, x, W1t, nullptr, nullptr,
                                        nullptr, 0.f, a_src, a_dst, as_out, ad_out, out_h,
                                        nrows);
    }
}

// conv2 wrapper: BN1 inline + 1-head attention
__global__ __launch_bounds__(256) void conv2_kernel(const _Float16* __restrict__ A,
                                                    const _Float16* __restrict__ Wt,
                                                    const float* __restrict__ bnpart,
                                                    const float* __restrict__ gamma,
                                                    const float* __restrict__ beta, float invN,
                                                    const float* __restrict__ a_src,
                                                    const float* __restrict__ a_dst,
                                                    float* __restrict__ as_out,
                                                    float* __restrict__ ad_out,
                                                    _Float16* __restrict__ out_h, int nrows) {
    gemm_body<128, true, 1, _Float16>(blockIdx.x, A, Wt, bnpart, gamma, beta, invN,
                                      a_src, a_dst, as_out, ad_out, out_h, nrows);
}

// ---------------- fused residual + final GEMM (BN2 inline) ----------------
// Phase 1: res = x @ Wres + b_res -> LDS tile (f16).
// Phase 2: out = ((relu(bn2(nb)) + res) * INV_SQRT2) @ Wfin + b_fin (fp32 out).

__global__ __launch_bounds__(256) void final_fused(const float* __restrict__ x,
                                                   const _Float16* __restrict__ nb,
                                                   const _Float16* __restrict__ Wrt,
                                                   const _Float16* __restrict__ Wft,
                                                   const float* __restrict__ b_res,
                                                   const float* __restrict__ bnpart,
                                                   const float* __restrict__ gamma,
                                                   const float* __restrict__ beta, float invN,
                                                   const float* __restrict__ b_fin,
                                                   float* __restrict__ out, int nrows) {
    __shared__ __align__(16) _Float16 Wr[128 * 136];   // 34 KB
    __shared__ __align__(16) _Float16 Wf[32 * 136];    // 8.5 KB
    __shared__ __align__(16) _Float16 Rt[128 * 136];   // 34 KB res tile
    __shared__ __align__(16) float bnsc[128], bnsh[128];
    int tid = threadIdx.x;
    {
        const float4* srcp = (const float4*)Wrt;
        float4* dstp = (float4*)Wr;
        for (int i = tid; i < 128 * 17; i += 256) dstp[i] = srcp[i];
        const float4* srcf = (const float4*)Wft;
        float4* dstf = (float4*)Wf;
        for (int i = tid; i < 32 * 17; i += 256) dstf[i] = srcf[i];
    }
    if (tid < 128) {
        float s = 0.f, q = 0.f;
#pragma unroll 8
        for (int k = 0; k < NPART; ++k) {
            s += bnpart[k * 256 + tid];
            q += bnpart[k * 256 + 128 + tid];
        }
        float mean = s * invN;
        float var = q * invN - mean * mean;
        float sc = gamma[tid] * rsqrtf(var + 1e-5f);
        bnsc[tid] = sc;
        bnsh[tid] = beta[tid] - mean * sc;
    }
    __syncthreads();

    int wave = tid >> 6, lane = tid & 63;
    int lrow = lane & 15, quad = lane >> 4;
    int m0 = blockIdx.x * 128 + wave * 32;
    long r0 = min(m0 + lrow, nrows - 1);
    long r1 = min(m0 + 16 + lrow, nrows - 1);

    // ---- phase 1: res GEMM (fp32 A from x) ----
    floatx4 acc[2][8];
#pragma unroll
    for (int ms = 0; ms < 2; ++ms)
#pragma unroll
        for (int nt = 0; nt < 8; ++nt) acc[ms][nt] = (floatx4){0.f, 0.f, 0.f, 0.f};
#pragma unroll
    for (int ks = 0; ks < 4; ++ks) {
        int k0 = ks * 32 + quad * 8;
        half8 a0h, a1h;
        {
            float4 f0 = *(const float4*)&x[r0 * 128 + k0];
            float4 f1 = *(const float4*)&x[r0 * 128 + k0 + 4];
            float4 g0 = *(const float4*)&x[r1 * 128 + k0];
            float4 g1 = *(const float4*)&x[r1 * 128 + k0 + 4];
            a0h[0] = (_Float16)f0.x; a0h[1] = (_Float16)f0.y;
            a0h[2] = (_Float16)f0.z; a0h[3] = (_Float16)f0.w;
            a0h[4] = (_Float16)f1.x; a0h[5] = (_Float16)f1.y;
            a0h[6] = (_Float16)f1.z; a0h[7] = (_Float16)f1.w;
            a1h[0] = (_Float16)g0.x; a1h[1] = (_Float16)g0.y;
            a1h[2] = (_Float16)g0.z; a1h[3] = (_Float16)g0.w;
            a1h[4] = (_Float16)g1.x; a1h[5] = (_Float16)g1.y;
            a1h[6] = (_Float16)g1.z; a1h[7] = (_Float16)g1.w;
        }
#pragma unroll
        for (int nt = 0; nt < 8; ++nt) {
            half8 b = *(half8*)&Wr[(nt * 16 + lrow) * 136 + k0];
            acc[0][nt] = __builtin_amdgcn_mfma_f32_16x16x32_f16(a0h, b, acc[0][nt], 0, 0, 0);
            acc[1][nt] = __builtin_amdgcn_mfma_f32_16x16x32_f16(a1h, b, acc[1][nt], 0, 0, 0);
        }
    }
#pragma unroll
    for (int ms = 0; ms < 2; ++ms) {
#pragma unroll
        for (int nt = 0; nt < 8; ++nt) {
            int col = nt * 16 + lrow;
            float bv = b_res[col];
#pragma unroll
            for (int reg = 0; reg < 4; ++reg) {
                int lr = wave * 32 + ms * 16 + quad * 4 + reg;
                Rt[lr * 136 + col] = (_Float16)(acc[ms][nt][reg] + bv);
            }
        }
    }
    __syncthreads();

    // ---- phase 2: final GEMM (A = (relu(bn2(nb)) + res) * inv_sqrt2) ----
    floatx4 fac[2][2];
#pragma unroll
    for (int ms = 0; ms < 2; ++ms)
#pragma unroll
        for (int nt = 0; nt < 2; ++nt) fac[ms][nt] = (floatx4){0.f, 0.f, 0.f, 0.f};
#pragma unroll
    for (int ks = 0; ks < 4; ++ks) {
        int k0 = ks * 32 + quad * 8;
        float4 sc0 = *(const float4*)&bnsc[k0];
        float4 sc1 = *(const float4*)&bnsc[k0 + 4];
        float4 sh0 = *(const float4*)&bnsh[k0];
        float4 sh1 = *(const float4*)&bnsh[k0 + 4];
        float scv[8] = {sc0.x, sc0.y, sc0.z, sc0.w, sc1.x, sc1.y, sc1.z, sc1.w};
        float shv[8] = {sh0.x, sh0.y, sh0.z, sh0.w, sh1.x, sh1.y, sh1.z, sh1.w};
        half8 n0 = *(const half8*)&nb[r0 * 128 + k0];
        half8 n1 = *(const half8*)&nb[r1 * 128 + k0];
        int lr0 = wave * 32 + lrow;
        int lr1 = wave * 32 + 16 + lrow;
        half8 e0 = *(const half8*)&Rt[lr0 * 136 + k0];
        half8 e1 = *(const half8*)&Rt[lr1 * 136 + k0];
        half8 a0h, a1h;
#pragma unroll
        for (int u = 0; u < 8; ++u) {
            float v0 = fmaxf((float)n0[u] * scv[u] + shv[u], 0.f);
            float v1 = fmaxf((float)n1[u] * scv[u] + shv[u], 0.f);
            a0h[u] = (_Float16)((v0 + (float)e0[u]) * INV_SQRT2);
            a1h[u] = (_Float16)((v1 + (float)e1[u]) * INV_SQRT2);
        }
#pragma unroll
        for (int nt = 0; nt < 2; ++nt) {
            half8 b = *(half8*)&Wf[(nt * 16 + lrow) * 136 + k0];
            fac[0][nt] = __builtin_amdgcn_mfma_f32_16x16x32_f16(a0h, b, fac[0][nt], 0, 0, 0);
            fac[1][nt] = __builtin_amdgcn_mfma_f32_16x16x32_f16(a1h, b, fac[1][nt], 0, 0, 0);
        }
    }
#pragma unroll
    for (int ms = 0; ms < 2; ++ms) {
#pragma unroll
        for (int nt = 0; nt < 2; ++nt) {
            int col = nt * 16 + lrow;
            float bv = b_fin[col];
#pragma unroll
            for (int reg = 0; reg < 4; ++reg) {
                int r = m0 + ms * 16 + quad * 4 + reg;
                if (r < nrows) out[(long)r * 32 + col] = fac[ms][nt][reg] + bv;
            }
        }
    }
}

// ---------------- GAT aggregation: alpha computed inline ----------------
// wave/node; group g = lane>>4 handles edges j+g+4k, k=0..3; lane covers 8 channels.
// softmax shift-invariant; logits O(3) so exp cannot overflow.

__global__ __launch_bounds__(256) void gat_agg_h4(const _Float16* __restrict__ h,
                                                  const float* __restrict__ as,
                                                  const float* __restrict__ ad,
                                                  const int* __restrict__ row_ptr,
                                                  const int* __restrict__ csr_src,
                                                  const float* __restrict__ bias,
                                                  _Float16* __restrict__ out, int n) {
    long gt = blockIdx.x * (long)blockDim.x + threadIdx.x;
    int node = (int)(gt >> 6);
    if (node >= n) return;
    int lane = threadIdx.x & 63;
    int lg = lane & 15, g = lane >> 4;
    int hh = lg >> 2;
    int start = row_ptr[node], end = row_ptr[node + 1];
    float adh = ad[node * 4 + hh];
    float acc[8] = {0, 0, 0, 0, 0, 0, 0, 0};
    float t = 0.f;
    for (int j = start; j < end; j += 16) {
        int s[4];
        float av[4];
#pragma unroll
        for (int k = 0; k < 4; ++k) {
            int je = j + g + 4 * k;
            bool vk = je < end;
            int jc = vk ? je : start;
            s[k] = csr_src[jc];
            av[k] = vk ? 1.f : 0.f;
        }
        float asv[4];
#pragma unroll
        for (int k = 0; k < 4; ++k) asv[k] = as[s[k] * 4 + hh];
        half8 hv[4];
#pragma unroll
        for (int k = 0; k < 4; ++k) hv[k] = *(const half8*)&h[(long)s[k] * 128 + lg * 8];
#pragma unroll
        for (int k = 0; k < 4; ++k) {
            float a = av[k] * __expf(lrelu(asv[k] + adh));
            t += a;
#pragma unroll
            for (int u = 0; u < 8; ++u) acc[u] += (float)hv[k][u] * a;
        }
    }
#pragma unroll
    for (int off = 16; off < 64; off <<= 1) {
        t += __shfl_xor(t, off);
#pragma unroll
        for (int u = 0; u < 8; ++u) acc[u] += __shfl_xor(acc[u], off);
    }
    if (g == 0) {
        float inv = 1.f / (t + 1e-16f);
        int cb = lg * 8;
        float4 b0 = *(const float4*)&bias[cb];
        float4 b1 = *(const float4*)&bias[cb + 4];
        half8 o;
        o[0] = (_Float16)(acc[0] * inv + b0.x);
        o[1] = (_Float16)(acc[1] * inv + b0.y);
        o[2] = (_Float16)(acc[2] * inv + b0.z);
        o[3] = (_Float16)(acc[3] * inv + b0.w);
        o[4] = (_Float16)(acc[4] * inv + b1.x);
        o[5] = (_Float16)(acc[5] * inv + b1.y);
        o[6] = (_Float16)(acc[6] * inv + b1.z);
        o[7] = (_Float16)(acc[7] * inv + b1.w);
        *(half8*)&out[(long)node * 128 + cb] = o;
    }
}

__global__ __launch_bounds__(256) void gat_agg_h1(const _Float16* __restrict__ h,
                                                  const float* __restrict__ as,
                                                  const float* __restrict__ ad,
                                                  const int* __restrict__ row_ptr,
                                                  const int* __restrict__ csr_src,
                                                  const float* __restrict__ bias,
                                                  _Float16* __restrict__ out, int n) {
    long gt = blockIdx.x * (long)blockDim.x + threadIdx.x;
    int node = (int)(gt >> 6);
    if (node >= n) return;
    int lane = threadIdx.x & 63;
    int lg = lane & 15, g = lane >> 4;
    int start = row_ptr[node], end = row_ptr[node + 1];
    float adn = ad[node];
    float acc[8] = {0, 0, 0, 0, 0, 0, 0, 0};
    float t = 0.f;
    for (int j = start; j < end; j += 16) {
        int s[4];
        float av[4];
#pragma unroll
        for (int k = 0; k < 4; ++k) {
            int je = j + g + 4 * k;
            bool vk = je < end;
            int jc = vk ? je : start;
            s[k] = csr_src[jc];
            av[k] = vk ? 1.f : 0.f;
        }
        float asv[4];
#pragma unroll
        for (int k = 0; k < 4; ++k) asv[k] = as[s[k]];
        half8 hv[4];
#pragma unroll
        for (int k = 0; k < 4; ++k) hv[k] = *(const half8*)&h[(long)s[k] * 128 + lg * 8];
#pragma unroll
        for (int k = 0; k < 4; ++k) {
            float a = av[k] * __expf(lrelu(asv[k] + adn));
            t += a;
#pragma unroll
            for (int u = 0; u < 8; ++u) acc[u] += (float)hv[k][u] * a;
        }
    }
#pragma unroll
    for (int off = 16; off < 64; off <<= 1) {
        t += __shfl_xor(t, off);
#pragma unroll
        for (int u = 0; u < 8; ++u) acc[u] += __shfl_xor(acc[u], off);
    }
    if (g == 0) {
        float inv = 1.f / (t + 1e-16f);
        int cb = lg * 8;
        float4 b0 = *(const float4*)&bias[cb];
        float4 b1 = *(const float4*)&bias[cb + 4];
        half8 o;
        o[0] = (_Float16)(acc[0] * inv + b0.x);
        o[1] = (_Float16)(acc[1] * inv + b0.y);
        o[2] = (_Float16)(acc[2] * inv + b0.z);
        o[3] = (_Float16)(acc[3] * inv + b0.w);
        o[4] = (_Float16)(acc[4] * inv + b1.x);
        o[5] = (_Float16)(acc[5] * inv + b1.y);
        o[6] = (_Float16)(acc[6] * inv + b1.z);
        o[7] = (_Float16)(acc[7] * inv + b1.w);
        *(half8*)&out[(long)node * 128 + cb] = o;
    }
}

// ---------------- BatchNorm stage 1: deterministic per-block partials ----------------

__global__ __launch_bounds__(256) void bn_part(const _Float16* __restrict__ h,
                                               float* __restrict__ partial, int n) {
    int tid = threadIdx.x;
    int lg = tid & 15;
    int rg = tid >> 4;   // 0..15
    int b = blockIdx.x;
    int chunk = (n + gridDim.x - 1) / (int)gridDim.x;
    int r0 = b * chunk;
    int r1 = min(r0 + chunk, n);
    float fs[8] = {0, 0, 0, 0, 0, 0, 0, 0};
    float fq[8] = {0, 0, 0, 0, 0, 0, 0, 0};
    for (int r = r0 + rg; r < r1; r += 16) {
        half8 hv = *(const half8*)&h[(long)r * 128 + lg * 8];
#pragma unroll
        for (int u = 0; u < 8; ++u) {
            float v = (float)hv[u];
            fs[u] += v;
            fq[u] += v * v;
        }
    }
#pragma unroll
    for (int off = 16; off < 64; off <<= 1) {
#pragma unroll
        for (int u = 0; u < 8; ++u) {
            fs[u] += __shfl_xor(fs[u], off);
            fq[u] += __shfl_xor(fq[u], off);
        }
    }
    __shared__ float reds[4][128], redq[4][128];
    int wave = tid >> 6, lane = tid & 63;
    if (lane < 16) {
#pragma unroll
        for (int u = 0; u < 8; ++u) {
            reds[wave][lane * 8 + u] = fs[u];
            redq[wave][lane * 8 + u] = fq[u];
        }
    }
    __syncthreads();
    if (tid < 128) {
        float s = reds[0][tid] + reds[1][tid] + reds[2][tid] + reds[3][tid];
        float q = redq[0][tid] + redq[1][tid] + redq[2][tid] + redq[3][tid];
        partial[b * 256 + tid] = s;
        partial[b * 256 + 128 + tid] = q;
    }
}

// ---------------- launch ----------------

extern "C" void kernel_launch(void* const* d_in, const int* in_sizes, int n_in,
                              void* d_out, int out_size, void* d_ws, size_t ws_size,
                              hipStream_t stream) {
    const float* x        = (const float*)d_in[0];
    const int*   ei       = (const int*)d_in[1];
    const float* W1       = (const float*)d_in[2];
    const float* att_src1 = (const float*)d_in[3];
    const float* att_dst1 = (const float*)d_in[4];
    const float* bias1    = (const float*)d_in[5];
    const float* W2       = (const float*)d_in[6];
    const float* att_src2 = (const float*)d_in[7];
    const float* att_dst2 = (const float*)d_in[8];
    const float* bias2    = (const float*)d_in[9];
    const float* gamma1   = (const float*)d_in[10];
    const float* beta1    = (const float*)d_in[11];
    const float* gamma2   = (const float*)d_in[12];
    const float* beta2    = (const float*)d_in[13];
    const float* W_res    = (const float*)d_in[14];
    const float* b_res    = (const float*)d_in[15];
    const float* W_fin    = (const float*)d_in[16];
    const float* b_fin    = (const float*)d_in[17];
    float* out = (float*)d_out;

    const int N = in_sizes[0] / 128;
    const int E = in_sizes[1] / 2;
    const int M = E + N;
    const int NB = (N + 255) >> 8;   // 196 coarse buckets
    const int* srcA = ei;
    const int* dstA = ei + E;

    char* w = (char*)d_ws;
    size_t off = 0;
    auto alloc = [&](size_t bytes) -> void* {
        off = (off + 255) & ~(size_t)255;
        void* p = w + off;
        off += bytes;
        return p;
    };
    __half*    hb      = (__half*)alloc((size_t)N * 128 * 2);        // conv outputs
    _Float16*  nb      = (_Float16*)alloc((size_t)N * 128 * 2);      // agg outputs (both layers)
    unsigned*  staging = (unsigned*)alloc((size_t)NB * BCAP * 4);    // packed 4B/entry
    int*       csr     = (int*)alloc((size_t)M * 4);
    int*       row_ptr = (int*)alloc((size_t)(N + 1) * 4);
    int*       bfill   = (int*)alloc((size_t)256 * 4);
    float*     bnpart  = (float*)alloc((size_t)NPART * 256 * 4);
    float*     as1     = (float*)alloc((size_t)N * 4 * 4);
    float*     ad1     = (float*)alloc((size_t)N * 4 * 4);
    float*     as2     = (float*)alloc((size_t)N * 4);
    float*     ad2     = (float*)alloc((size_t)N * 4);
    _Float16*  W1t     = (_Float16*)alloc((size_t)128 * 136 * 2);
    _Float16*  W2t     = (_Float16*)alloc((size_t)128 * 136 * 2);
    _Float16*  Wrt     = (_Float16*)alloc((size_t)128 * 136 * 2);
    _Float16*  Wft     = (_Float16*)alloc((size_t)32 * 136 * 2);

    const int grid_mfma  = (N + 127) / 128;
    const int grid_nodes = (N + 3) / 4;
    const int scat_blks  = 256;
    const int chunk      = (M + scat_blks - 1) / scat_blks;
    const float invN = 1.0f / (float)N;

    // weight prep (also zeroes bfill — must precede scatter_conv1)
    prep_weights<<<208, 256, 0, stream>>>(W1, W2, W_res, W_fin, W1t, W2t, Wrt, Wft, bfill);

    // bucket_scatter + conv1 (+fused 4-head attention) in one dispatch (independent work)
    scatter_conv1<<<scat_blks + grid_mfma, 256, 0, stream>>>(
        srcA, dstA, bfill, staging, E, N, chunk, scat_blks,
        x, W1t, att_src1, att_dst1, as1, ad1, (_Float16*)hb, N);

    fine_sort<<<NB, 256, 0, stream>>>(staging, bfill, row_ptr, csr, NB, N);

    gat_agg_h4<<<grid_nodes, 256, 0, stream>>>((const _Float16*)hb, as1, ad1, row_ptr, csr,
                                               bias1, nb, N);

    // BN1 partials (finalize inline in conv2)
    bn_part<<<NPART, 256, 0, stream>>>(nb, bnpart, N);

    // conv2: relu(bn1(nb)) @ W2 (+fused 1-head attention, BN1 reduced inline)
    conv2_kernel<<<grid_mfma, 256, 0, stream>>>(nb, W2t, bnpart, gamma1, beta1, invN,
                                                att_src2, att_dst2, as2, ad2,
                                                (_Float16*)hb, N);

    gat_agg_h1<<<grid_nodes, 256, 0, stream>>>((const _Float16*)hb, as2, ad2, row_ptr, csr,
                                               bias2, nb, N);

    // BN2 partials (finalize inline in final_fused)
    bn_part<<<NPART, 256, 0, stream>>>(nb, bnpart, N);

    // fused: res = x@Wres+b_res (LDS); out = ((relu(bn2(nb))+res)*c) @ Wfin + b_fin
    final_fused<<<grid_mfma, 256, 0, stream>>>(x, nb, Wrt, Wft, b_res, bnpart, gamma2, beta2,
                                               invN, b_fin, out, N);
}

// Round 14
// 261.760 us; speedup vs baseline: 1.1604x; 1.1604x over previous
//
#include <hip/hip_runtime.h>
#include <hip/hip_fp16.h>
#include <type_traits>

#define NEG_SLOPE 0.2f
#define INV_SQRT2 0.7071067811865476f
#define BCAP 8192   // padded per-bucket staging capacity (avg ~4337 edges/bucket)

typedef _Float16 half8 __attribute__((ext_vector_type(8)));
typedef float floatx4 __attribute__((ext_vector_type(4)));

__device__ __forceinline__ float lrelu(float x) { return x > 0.f ? x : NEG_SLOPE * x; }

// ---------------- weight prep + bfill zero (runs first, so no memset dispatch) ----------------

__global__ __launch_bounds__(256) void prep_weights(const float* __restrict__ W1,
                                                    const float* __restrict__ W2,
                                                    const float* __restrict__ Wres,
                                                    const float* __restrict__ Wfin,
                                                    _Float16* __restrict__ W1t,
                                                    _Float16* __restrict__ W2t,
                                                    _Float16* __restrict__ Wrt,
                                                    _Float16* __restrict__ Wft,
                                                    int* __restrict__ bfill) {
    if (blockIdx.x == 0) bfill[threadIdx.x] = 0;
    int i = blockIdx.x * 256 + threadIdx.x;
    if (i < 16384) {
        int k = i >> 7, n = i & 127;
        W1t[n * 136 + k] = (_Float16)W1[i];
    } else if (i < 32768) {
        int j = i - 16384; int k = j >> 7, n = j & 127;
        W2t[n * 136 + k] = (_Float16)W2[j];
    } else if (i < 49152) {
        int j = i - 32768; int k = j >> 7, n = j & 127;
        Wrt[n * 136 + k] = (_Float16)Wres[j];
    } else if (i < 53248) {
        int j = i - 49152; int k = j >> 5, n = j & 31;
        Wft[n * 136 + k] = (_Float16)Wfin[j];
    }
}

// ---------------- CSR build: two-level bucket sort by dst ----------------
// staging entry packed: src (24 bits) | (dst & 255) << 24

__global__ __launch_bounds__(256) void bucket_scatter(const int* __restrict__ src,
                                                      const int* __restrict__ dst,
                                                      int* __restrict__ bucket_fill,
                                                      unsigned* __restrict__ staging,
                                                      int E, int N, int chunk) {
    __shared__ int lds[256];
    int tid = threadIdx.x;
    int M = E + N;
    int begin = blockIdx.x * chunk;
    int endc = min(begin + chunk, M);
    lds[tid] = 0;
    __syncthreads();
    for (int i = begin + tid; i < endc; i += 256) {
        int d = (i < E) ? dst[i] : (i - E);
        atomicAdd(&lds[d >> 8], 1);
    }
    __syncthreads();
    int h = lds[tid];
    int base = 0;
    if (h > 0) base = atomicAdd(&bucket_fill[tid], h);
    __syncthreads();
    lds[tid] = base;
    __syncthreads();
    for (int i = begin + tid; i < endc; i += 256) {
        int s, d;
        if (i < E) { s = src[i]; d = dst[i]; } else { s = d = i - E; }
        int b = d >> 8;
        int r = atomicAdd(&lds[b], 1);
        if (r < BCAP) staging[b * BCAP + r] = (unsigned)s | ((unsigned)(d & 255) << 24);
    }
}

__global__ __launch_bounds__(256) void fine_sort(const unsigned* __restrict__ staging,
                                                 const int* __restrict__ bucket_fill,
                                                 int* __restrict__ row_ptr,
                                                 int* __restrict__ csr_src, int NB, int N) {
    __shared__ int sb[256];
    __shared__ int c1[256];
    __shared__ int s1[256];
    int t = threadIdx.x;
    int b = blockIdx.x;
    int c = (t < NB) ? min(bucket_fill[t], BCAP) : 0;
    sb[t] = c;
    __syncthreads();
    for (int off = 1; off < 256; off <<= 1) {
        int add = (t >= off) ? sb[t - off] : 0;
        __syncthreads();
        sb[t] += add;
        __syncthreads();
    }
    int hi = sb[b];
    int lo = (b > 0) ? sb[b - 1] : 0;
    int cnt = hi - lo;
    if (b == NB - 1 && t == 0) row_ptr[N] = sb[NB - 1];
    const unsigned* stg = staging + (long)b * BCAP;
    c1[t] = 0;
    __syncthreads();
    for (int k = t; k < cnt; k += 256) atomicAdd(&c1[stg[k] >> 24], 1);
    __syncthreads();
    int v = c1[t];
    s1[t] = v;
    __syncthreads();
    for (int off = 1; off < 256; off <<= 1) {
        int add = (t >= off) ? s1[t - off] : 0;
        __syncthreads();
        s1[t] += add;
        __syncthreads();
    }
    int excl = s1[t] - v;
    int node = b * 256 + t;
    if (node < N) row_ptr[node] = lo + excl;
    c1[t] = lo + excl;   // cursor
    __syncthreads();
    for (int k = t; k < cnt; k += 256) {
        unsigned e = stg[k];
        int p = atomicAdd(&c1[e >> 24], 1);
        csr_src[p] = (int)(e & 0xFFFFFFu);
    }
}

// ---------------- MFMA f16 GEMM + fused attention coefficients ----------------
// A-layout (verified): lane supplies A[m = lane&15][k = quad*8 + j]. W staged in LDS only.
// ATTN = 0 (none) / 1 / 4 heads: as/ad computed from fp32 accumulators in the epilogue;
// a row's 128 channels live in the 16 lanes of its quad-group (8 regs x lrow), so the
// dot-product reduce is shfl_xor over offsets 1,2,4,8 (stays within the 16-lane group).

template <int NCOLS, bool DO_BN, int ATTN, typename AT>
__global__ __launch_bounds__(256) void mfma_gemm(const AT* __restrict__ A,
                                                 const _Float16* __restrict__ Wt,
                                                 const float* __restrict__ sc_,
                                                 const float* __restrict__ sh_,
                                                 const float* __restrict__ a_src,
                                                 const float* __restrict__ a_dst,
                                                 float* __restrict__ as_out,
                                                 float* __restrict__ ad_out,
                                                 _Float16* __restrict__ out_h,
                                                 int nrows) {
    __shared__ __align__(16) _Float16 Ws[NCOLS * 136];
    int tid = threadIdx.x;
    {
        const float4* srcp = (const float4*)Wt;
        float4* dstp = (float4*)Ws;
        for (int i = tid; i < NCOLS * 17; i += 256) dstp[i] = srcp[i];
    }
    __syncthreads();

    int wave = tid >> 6, lane = tid & 63;
    int lrow = lane & 15, quad = lane >> 4;
    int m0 = blockIdx.x * 128 + wave * 32;
    long r0 = min(m0 + lrow, nrows - 1);
    long r1 = min(m0 + 16 + lrow, nrows - 1);
    constexpr int NT = NCOLS / 16;
    floatx4 acc[2][NT];
#pragma unroll
    for (int ms = 0; ms < 2; ++ms)
#pragma unroll
        for (int nt = 0; nt < NT; ++nt) acc[ms][nt] = (floatx4){0.f, 0.f, 0.f, 0.f};

#pragma unroll
    for (int ks = 0; ks < 4; ++ks) {
        int k0 = ks * 32 + quad * 8;
        float av[2][8];
        if constexpr (std::is_same<AT, float>::value) {
            float4 f0 = *(const float4*)&A[r0 * 128 + k0];
            float4 f1 = *(const float4*)&A[r0 * 128 + k0 + 4];
            av[0][0] = f0.x; av[0][1] = f0.y; av[0][2] = f0.z; av[0][3] = f0.w;
            av[0][4] = f1.x; av[0][5] = f1.y; av[0][6] = f1.z; av[0][7] = f1.w;
            float4 g0 = *(const float4*)&A[r1 * 128 + k0];
            float4 g1 = *(const float4*)&A[r1 * 128 + k0 + 4];
            av[1][0] = g0.x; av[1][1] = g0.y; av[1][2] = g0.z; av[1][3] = g0.w;
            av[1][4] = g1.x; av[1][5] = g1.y; av[1][6] = g1.z; av[1][7] = g1.w;
        } else {
            half8 h0 = *(const half8*)&A[r0 * 128 + k0];
            half8 h1 = *(const half8*)&A[r1 * 128 + k0];
#pragma unroll
            for (int u = 0; u < 8; ++u) {
                av[0][u] = (float)h0[u];
                av[1][u] = (float)h1[u];
            }
        }
        if (DO_BN) {
            float4 sc0 = *(const float4*)&sc_[k0];
            float4 sc1 = *(const float4*)&sc_[k0 + 4];
            float4 sh0 = *(const float4*)&sh_[k0];
            float4 sh1 = *(const float4*)&sh_[k0 + 4];
            float scv[8] = {sc0.x, sc0.y, sc0.z, sc0.w, sc1.x, sc1.y, sc1.z, sc1.w};
            float shv[8] = {sh0.x, sh0.y, sh0.z, sh0.w, sh1.x, sh1.y, sh1.z, sh1.w};
#pragma unroll
            for (int ms = 0; ms < 2; ++ms)
#pragma unroll
                for (int u = 0; u < 8; ++u)
                    av[ms][u] = fmaxf(av[ms][u] * scv[u] + shv[u], 0.f);
        }
        half8 a0h, a1h;
#pragma unroll
        for (int u = 0; u < 8; ++u) {
            a0h[u] = (_Float16)av[0][u];
            a1h[u] = (_Float16)av[1][u];
        }
#pragma unroll
        for (int nt = 0; nt < NT; ++nt) {
            half8 b = *(half8*)&Ws[(nt * 16 + lrow) * 136 + k0];
            acc[0][nt] = __builtin_amdgcn_mfma_f32_16x16x32_f16(a0h, b, acc[0][nt], 0, 0, 0);
            acc[1][nt] = __builtin_amdgcn_mfma_f32_16x16x32_f16(a1h, b, acc[1][nt], 0, 0, 0);
        }
    }

    // epilogue: C/D layout col=lane&15, row=quad*4+reg
#pragma unroll
    for (int ms = 0; ms < 2; ++ms) {
#pragma unroll
        for (int nt = 0; nt < NT; ++nt) {
            int col = nt * 16 + lrow;
#pragma unroll
            for (int reg = 0; reg < 4; ++reg) {
                int r = m0 + ms * 16 + quad * 4 + reg;
                if (r < nrows) out_h[(long)r * NCOLS + col] = (_Float16)acc[ms][nt][reg];
            }
        }
    }

    if constexpr (ATTN > 0) {
        float asrc_l[NT], adst_l[NT];
#pragma unroll
        for (int nt = 0; nt < NT; ++nt) {
            asrc_l[nt] = a_src[nt * 16 + lrow];
            adst_l[nt] = a_dst[nt * 16 + lrow];
        }
#pragma unroll
        for (int ms = 0; ms < 2; ++ms) {
#pragma unroll
            for (int reg = 0; reg < 4; ++reg) {
                int r = m0 + ms * 16 + quad * 4 + reg;
                if constexpr (ATTN == 4) {
                    // head h owns cols [32h, 32h+32) = nt 2h, 2h+1
                    float ps[4], pd[4];
#pragma unroll
                    for (int h = 0; h < 4; ++h) {
                        ps[h] = acc[ms][2 * h][reg] * asrc_l[2 * h] +
                                acc[ms][2 * h + 1][reg] * asrc_l[2 * h + 1];
                        pd[h] = acc[ms][2 * h][reg] * adst_l[2 * h] +
                                acc[ms][2 * h + 1][reg] * adst_l[2 * h + 1];
                    }
#pragma unroll
                    for (int off = 1; off < 16; off <<= 1) {
#pragma unroll
                        for (int h = 0; h < 4; ++h) {
                            ps[h] += __shfl_xor(ps[h], off);
                            pd[h] += __shfl_xor(pd[h], off);
                        }
                    }
                    if (r < nrows && lrow < 4) {
                        float psv = lrow == 0 ? ps[0] : lrow == 1 ? ps[1]
                                  : lrow == 2 ? ps[2] : ps[3];
                        float pdv = lrow == 0 ? pd[0] : lrow == 1 ? pd[1]
                                  : lrow == 2 ? pd[2] : pd[3];
                        as_out[r * 4 + lrow] = psv;
                        ad_out[r * 4 + lrow] = pdv;
                    }
                } else {
                    float ps = 0.f, pd = 0.f;
#pragma unroll
                    for (int nt = 0; nt < NT; ++nt) {
                        ps += acc[ms][nt][reg] * asrc_l[nt];
                        pd += acc[ms][nt][reg] * adst_l[nt];
                    }
#pragma unroll
                    for (int off = 1; off < 16; off <<= 1) {
                        ps += __shfl_xor(ps, off);
                        pd += __shfl_xor(pd, off);
                    }
                    if (r < nrows && lrow == 0) {
                        as_out[r] = ps;
                        ad_out[r] = pd;
                    }
                }
            }
        }
    }
}

// ---------------- fused residual + final GEMM ----------------
// Phase 1: res = x @ Wres + b_res for this block's 128 rows -> LDS tile (f16).
// Phase 2: out = ((relu(bn2(nb)) + res) * INV_SQRT2) @ Wfin + b_fin (fp32 out).

__global__ __launch_bounds__(256) void final_fused(const float* __restrict__ x,
                                                   const _Float16* __restrict__ nb,
                                                   const _Float16* __restrict__ Wrt,
                                                   const _Float16* __restrict__ Wft,
                                                   const float* __restrict__ b_res,
                                                   const float* __restrict__ sc_,
                                                   const float* __restrict__ sh_,
                                                   const float* __restrict__ b_fin,
                                                   float* __restrict__ out, int nrows) {
    __shared__ __align__(16) _Float16 Wr[128 * 136];   // 34 KB
    __shared__ __align__(16) _Float16 Wf[32 * 136];    // 8.5 KB
    __shared__ __align__(16) _Float16 Rt[128 * 136];   // 34 KB res tile
    int tid = threadIdx.x;
    {
        const float4* srcp = (const float4*)Wrt;
        float4* dstp = (float4*)Wr;
        for (int i = tid; i < 128 * 17; i += 256) dstp[i] = srcp[i];
        const float4* srcf = (const float4*)Wft;
        float4* dstf = (float4*)Wf;
        for (int i = tid; i < 32 * 17; i += 256) dstf[i] = srcf[i];
    }
    __syncthreads();

    int wave = tid >> 6, lane = tid & 63;
    int lrow = lane & 15, quad = lane >> 4;
    int m0 = blockIdx.x * 128 + wave * 32;
    long r0 = min(m0 + lrow, nrows - 1);
    long r1 = min(m0 + 16 + lrow, nrows - 1);

    // ---- phase 1: res GEMM (fp32 A from x) ----
    floatx4 acc[2][8];
#pragma unroll
    for (int ms = 0; ms < 2; ++ms)
#pragma unroll
        for (int nt = 0; nt < 8; ++nt) acc[ms][nt] = (floatx4){0.f, 0.f, 0.f, 0.f};
#pragma unroll
    for (int ks = 0; ks < 4; ++ks) {
        int k0 = ks * 32 + quad * 8;
        half8 a0h, a1h;
        {
            float4 f0 = *(const float4*)&x[r0 * 128 + k0];
            float4 f1 = *(const float4*)&x[r0 * 128 + k0 + 4];
            float4 g0 = *(const float4*)&x[r1 * 128 + k0];
            float4 g1 = *(const float4*)&x[r1 * 128 + k0 + 4];
            a0h[0] = (_Float16)f0.x; a0h[1] = (_Float16)f0.y;
            a0h[2] = (_Float16)f0.z; a0h[3] = (_Float16)f0.w;
            a0h[4] = (_Float16)f1.x; a0h[5] = (_Float16)f1.y;
            a0h[6] = (_Float16)f1.z; a0h[7] = (_Float16)f1.w;
            a1h[0] = (_Float16)g0.x; a1h[1] = (_Float16)g0.y;
            a1h[2] = (_Float16)g0.z; a1h[3] = (_Float16)g0.w;
            a1h[4] = (_Float16)g1.x; a1h[5] = (_Float16)g1.y;
            a1h[6] = (_Float16)g1.z; a1h[7] = (_Float16)g1.w;
        }
#pragma unroll
        for (int nt = 0; nt < 8; ++nt) {
            half8 b = *(half8*)&Wr[(nt * 16 + lrow) * 136 + k0];
            acc[0][nt] = __builtin_amdgcn_mfma_f32_16x16x32_f16(a0h, b, acc[0][nt], 0, 0, 0);
            acc[1][nt] = __builtin_amdgcn_mfma_f32_16x16x32_f16(a1h, b, acc[1][nt], 0, 0, 0);
        }
    }
#pragma unroll
    for (int ms = 0; ms < 2; ++ms) {
#pragma unroll
        for (int nt = 0; nt < 8; ++nt) {
            int col = nt * 16 + lrow;
            float bv = b_res[col];
#pragma unroll
            for (int reg = 0; reg < 4; ++reg) {
                int lr = wave * 32 + ms * 16 + quad * 4 + reg;
                Rt[lr * 136 + col] = (_Float16)(acc[ms][nt][reg] + bv);
            }
        }
    }
    __syncthreads();

    // ---- phase 2: final GEMM (A = (relu(bn2(nb)) + res) * inv_sqrt2) ----
    floatx4 fac[2][2];
#pragma unroll
    for (int ms = 0; ms < 2; ++ms)
#pragma unroll
        for (int nt = 0; nt < 2; ++nt) fac[ms][nt] = (floatx4){0.f, 0.f, 0.f, 0.f};
#pragma unroll
    for (int ks = 0; ks < 4; ++ks) {
        int k0 = ks * 32 + quad * 8;
        float4 sc0 = *(const float4*)&sc_[k0];
        float4 sc1 = *(const float4*)&sc_[k0 + 4];
        float4 sh0 = *(const float4*)&sh_[k0];
        float4 sh1 = *(const float4*)&sh_[k0 + 4];
        float scv[8] = {sc0.x, sc0.y, sc0.z, sc0.w, sc1.x, sc1.y, sc1.z, sc1.w};
        float shv[8] = {sh0.x, sh0.y, sh0.z, sh0.w, sh1.x, sh1.y, sh1.z, sh1.w};
        half8 n0 = *(const half8*)&nb[r0 * 128 + k0];
        half8 n1 = *(const half8*)&nb[r1 * 128 + k0];
        int lr0 = wave * 32 + lrow;
        int lr1 = wave * 32 + 16 + lrow;
        half8 e0 = *(const half8*)&Rt[lr0 * 136 + k0];
        half8 e1 = *(const half8*)&Rt[lr1 * 136 + k0];
        half8 a0h, a1h;
#pragma unroll
        for (int u = 0; u < 8; ++u) {
            float v0 = fmaxf((float)n0[u] * scv[u] + shv[u], 0.f);
            float v1 = fmaxf((float)n1[u] * scv[u] + shv[u], 0.f);
            a0h[u] = (_Float16)((v0 + (float)e0[u]) * INV_SQRT2);
            a1h[u] = (_Float16)((v1 + (float)e1[u]) * INV_SQRT2);
        }
#pragma unroll
        for (int nt = 0; nt < 2; ++nt) {
            half8 b = *(half8*)&Wf[(nt * 16 + lrow) * 136 + k0];
            fac[0][nt] = __builtin_amdgcn_mfma_f32_16x16x32_f16(a0h, b, fac[0][nt], 0, 0, 0);
            fac[1][nt] = __builtin_amdgcn_mfma_f32_16x16x32_f16(a1h, b, fac[1][nt], 0, 0, 0);
        }
    }
#pragma unroll
    for (int ms = 0; ms < 2; ++ms) {
#pragma unroll
        for (int nt = 0; nt < 2; ++nt) {
            int col = nt * 16 + lrow;
            float bv = b_fin[col];
#pragma unroll
            for (int reg = 0; reg < 4; ++reg) {
                int r = m0 + ms * 16 + quad * 4 + reg;
                if (r < nrows) out[(long)r * 32 + col] = fac[ms][nt][reg] + bv;
            }
        }
    }
}

// ---------------- GAT aggregation: alpha computed inline ----------------
// wave/node; group g = lane>>4 handles edges j+g+4k, k=0..3; lane covers 8 channels.
// softmax shift-invariant; logits O(3) so exp cannot overflow.

__global__ __launch_bounds__(256) void gat_agg_h4(const _Float16* __restrict__ h,
                                                  const float* __restrict__ as,
                                                  const float* __restrict__ ad,
                                                  const int* __restrict__ row_ptr,
                                                  const int* __restrict__ csr_src,
                                                  const float* __restrict__ bias,
                                                  _Float16* __restrict__ out, int n) {
    long gt = blockIdx.x * (long)blockDim.x + threadIdx.x;
    int node = (int)(gt >> 6);
    if (node >= n) return;
    int lane = threadIdx.x & 63;
    int lg = lane & 15, g = lane >> 4;
    int hh = lg >> 2;
    int start = row_ptr[node], end = row_ptr[node + 1];
    float adh = ad[node * 4 + hh];
    float acc[8] = {0, 0, 0, 0, 0, 0, 0, 0};
    float t = 0.f;
    for (int j = start; j < end; j += 16) {
        int s[4];
        float av[4];
#pragma unroll
        for (int k = 0; k < 4; ++k) {
            int je = j + g + 4 * k;
            bool vk = je < end;
            int jc = vk ? je : start;
            s[k] = csr_src[jc];
            av[k] = vk ? 1.f : 0.f;
        }
        float asv[4];
#pragma unroll
        for (int k = 0; k < 4; ++k) asv[k] = as[s[k] * 4 + hh];
        half8 hv[4];
#pragma unroll
        for (int k = 0; k < 4; ++k) hv[k] = *(const half8*)&h[(long)s[k] * 128 + lg * 8];
#pragma unroll
        for (int k = 0; k < 4; ++k) {
            float a = av[k] * __expf(lrelu(asv[k] + adh));
            t += a;
#pragma unroll
            for (int u = 0; u < 8; ++u) acc[u] += (float)hv[k][u] * a;
        }
    }
#pragma unroll
    for (int off = 16; off < 64; off <<= 1) {
        t += __shfl_xor(t, off);
#pragma unroll
        for (int u = 0; u < 8; ++u) acc[u] += __shfl_xor(acc[u], off);
    }
    if (g == 0) {
        float inv = 1.f / (t + 1e-16f);
        int cb = lg * 8;
        float4 b0 = *(const float4*)&bias[cb];
        float4 b1 = *(const float4*)&bias[cb + 4];
        half8 o;
        o[0] = (_Float16)(acc[0] * inv + b0.x);
        o[1] = (_Float16)(acc[1] * inv + b0.y);
        o[2] = (_Float16)(acc[2] * inv + b0.z);
        o[3] = (_Float16)(acc[3] * inv + b0.w);
        o[4] = (_Float16)(acc[4] * inv + b1.x);
        o[5] = (_Float16)(acc[5] * inv + b1.y);
        o[6] = (_Float16)(acc[6] * inv + b1.z);
        o[7] = (_Float16)(acc[7] * inv + b1.w);
        *(half8*)&out[(long)node * 128 + cb] = o;
    }
}

__global__ __launch_bounds__(256) void gat_agg_h1(const _Float16* __restrict__ h,
                                                  const float* __restrict__ as,
                                                  const float* __restrict__ ad,
                                                  const int* __restrict__ row_ptr,
                                                  const int* __restrict__ csr_src,
                                                  const float* __restrict__ bias,
                                                  _Float16* __restrict__ out, int n) {
    long gt = blockIdx.x * (long)blockDim.x + threadIdx.x;
    int node = (int)(gt >> 6);
    if (node >= n) return;
    int lane = threadIdx.x & 63;
    int lg = lane & 15, g = lane >> 4;
    int start = row_ptr[node], end = row_ptr[node + 1];
    float adn = ad[node];
    float acc[8] = {0, 0, 0, 0, 0, 0, 0, 0};
    float t = 0.f;
    for (int j = start; j < end; j += 16) {
        int s[4];
        float av[4];
#pragma unroll
        for (int k = 0; k < 4; ++k) {
            int je = j + g + 4 * k;
            bool vk = je < end;
            int jc = vk ? je : start;
            s[k] = csr_src[jc];
            av[k] = vk ? 1.f : 0.f;
        }
        float asv[4];
#pragma unroll
        for (int k = 0; k < 4; ++k) asv[k] = as[s[k]];
        half8 hv[4];
#pragma unroll
        for (int k = 0; k < 4; ++k) hv[k] = *(const half8*)&h[(long)s[k] * 128 + lg * 8];
#pragma unroll
        for (int k = 0; k < 4; ++k) {
            float a = av[k] * __expf(lrelu(asv[k] + adn));
            t += a;
#pragma unroll
            for (int u = 0; u < 8; ++u) acc[u] += (float)hv[k][u] * a;
        }
    }
#pragma unroll
    for (int off = 16; off < 64; off <<= 1) {
        t += __shfl_xor(t, off);
#pragma unroll
        for (int u = 0; u < 8; ++u) acc[u] += __shfl_xor(acc[u], off);
    }
    if (g == 0) {
        float inv = 1.f / (t + 1e-16f);
        int cb = lg * 8;
        float4 b0 = *(const float4*)&bias[cb];
        float4 b1 = *(const float4*)&bias[cb + 4];
        half8 o;
        o[0] = (_Float16)(acc[0] * inv + b0.x);
        o[1] = (_Float16)(acc[1] * inv + b0.y);
        o[2] = (_Float16)(acc[2] * inv + b0.z);
        o[3] = (_Float16)(acc[3] * inv + b0.w);
        o[4] = (_Float16)(acc[4] * inv + b1.x);
        o[5] = (_Float16)(acc[5] * inv + b1.y);
        o[6] = (_Float16)(acc[6] * inv + b1.z);
        o[7] = (_Float16)(acc[7] * inv + b1.w);
        *(half8*)&out[(long)node * 128 + cb] = o;
    }
}

// ---------------- BatchNorm: two-stage deterministic reduction (no atomics) ----------------

__global__ __launch_bounds__(256) void bn_part(const _Float16* __restrict__ h,
                                               float* __restrict__ partial, int n) {
    int tid = threadIdx.x;
    int lg = tid & 15;
    int rg = tid >> 4;   // 0..15
    int b = blockIdx.x;
    int chunk = (n + gridDim.x - 1) / (int)gridDim.x;
    int r0 = b * chunk;
    int r1 = min(r0 + chunk, n);
    float fs[8] = {0, 0, 0, 0, 0, 0, 0, 0};
    float fq[8] = {0, 0, 0, 0, 0, 0, 0, 0};
    for (int r = r0 + rg; r < r1; r += 16) {
        half8 hv = *(const half8*)&h[(long)r * 128 + lg * 8];
#pragma unroll
        for (int u = 0; u < 8; ++u) {
            float v = (float)hv[u];
            fs[u] += v;
            fq[u] += v * v;
        }
    }
#pragma unroll
    for (int off = 16; off < 64; off <<= 1) {
#pragma unroll
        for (int u = 0; u < 8; ++u) {
            fs[u] += __shfl_xor(fs[u], off);
            fq[u] += __shfl_xor(fq[u], off);
        }
    }
    __shared__ float reds[4][128], redq[4][128];
    int wave = tid >> 6, lane = tid & 63;
    if (lane < 16) {
#pragma unroll
        for (int u = 0; u < 8; ++u) {
            reds[wave][lane * 8 + u] = fs[u];
            redq[wave][lane * 8 + u] = fq[u];
        }
    }
    __syncthreads();
    if (tid < 128) {
        float s = reds[0][tid] + reds[1][tid] + reds[2][tid] + reds[3][tid];
        float q = redq[0][tid] + redq[1][tid] + redq[2][tid] + redq[3][tid];
        partial[b * 256 + tid] = s;
        partial[b * 256 + 128 + tid] = q;
    }
}

__global__ __launch_bounds__(1024) void bn_reduce(const float* __restrict__ partial,
                                                  const float* __restrict__ gamma,
                                                  const float* __restrict__ beta,
                                                  float* __restrict__ scale,
                                                  float* __restrict__ shift, float invN) {
    __shared__ float lds_s[8][128], lds_q[8][128];
    int c = threadIdx.x & 127;
    int sl = threadIdx.x >> 7;   // 0..7
    float s = 0.f, q = 0.f;
#pragma unroll 4
    for (int k = sl; k < 256; k += 8) {
        s += partial[k * 256 + c];
        q += partial[k * 256 + 128 + c];
    }
    lds_s[sl][c] = s;
    lds_q[sl][c] = q;
    __syncthreads();
    if (threadIdx.x < 128) {
        float S = 0.f, Q = 0.f;
#pragma unroll
        for (int i = 0; i < 8; ++i) { S += lds_s[i][c]; Q += lds_q[i][c]; }
        float mean = S * invN;
        float var = Q * invN - mean * mean;
        float sc = gamma[c] * rsqrtf(var + 1e-5f);
        scale[c] = sc;
        shift[c] = beta[c] - mean * sc;
    }
}

// ---------------- launch ----------------

extern "C" void kernel_launch(void* const* d_in, const int* in_sizes, int n_in,
                              void* d_out, int out_size, void* d_ws, size_t ws_size,
                              hipStream_t stream) {
    const float* x        = (const float*)d_in[0];
    const int*   ei       = (const int*)d_in[1];
    const float* W1       = (const float*)d_in[2];
    const float* att_src1 = (const float*)d_in[3];
    const float* att_dst1 = (const float*)d_in[4];
    const float* bias1    = (const float*)d_in[5];
    const float* W2       = (const float*)d_in[6];
    const float* att_src2 = (const float*)d_in[7];
    const float* att_dst2 = (const float*)d_in[8];
    const float* bias2    = (const float*)d_in[9];
    const float* gamma1   = (const float*)d_in[10];
    const float* beta1    = (const float*)d_in[11];
    const float* gamma2   = (const float*)d_in[12];
    const float* beta2    = (const float*)d_in[13];
    const float* W_res    = (const float*)d_in[14];
    const float* b_res    = (const float*)d_in[15];
    const float* W_fin    = (const float*)d_in[16];
    const float* b_fin    = (const float*)d_in[17];
    float* out = (float*)d_out;

    const int N = in_sizes[0] / 128;
    const int E = in_sizes[1] / 2;
    const int M = E + N;
    const int NB = (N + 255) >> 8;   // 196 coarse buckets
    const int* srcA = ei;
    const int* dstA = ei + E;

    char* w = (char*)d_ws;
    size_t off = 0;
    auto alloc = [&](size_t bytes) -> void* {
        off = (off + 255) & ~(size_t)255;
        void* p = w + off;
        off += bytes;
        return p;
    };
    __half*    hb      = (__half*)alloc((size_t)N * 128 * 2);        // conv outputs
    _Float16*  nb      = (_Float16*)alloc((size_t)N * 128 * 2);      // agg outputs (both layers)
    unsigned*  staging = (unsigned*)alloc((size_t)NB * BCAP * 4);    // packed 4B/entry
    int*       csr     = (int*)alloc((size_t)M * 4);
    int*       row_ptr = (int*)alloc((size_t)(N + 1) * 4);
    int*       bfill   = (int*)alloc((size_t)256 * 4);
    float*     bnpart  = (float*)alloc((size_t)256 * 256 * 4);
    float*     as1     = (float*)alloc((size_t)N * 4 * 4);
    float*     ad1     = (float*)alloc((size_t)N * 4 * 4);
    float*     as2     = (float*)alloc((size_t)N * 4);
    float*     ad2     = (float*)alloc((size_t)N * 4);
    _Float16*  W1t     = (_Float16*)alloc((size_t)128 * 136 * 2);
    _Float16*  W2t     = (_Float16*)alloc((size_t)128 * 136 * 2);
    _Float16*  Wrt     = (_Float16*)alloc((size_t)128 * 136 * 2);
    _Float16*  Wft     = (_Float16*)alloc((size_t)32 * 136 * 2);
    float*     scale1  = (float*)alloc(128 * 4);
    float*     shift1  = (float*)alloc(128 * 4);
    float*     scale2  = (float*)alloc(128 * 4);
    float*     shift2  = (float*)alloc(128 * 4);

    const int grid_mfma  = (N + 127) / 128;
    const int grid_nodes = (N + 3) / 4;
    const int scat_blks  = 256;
    const int chunk      = (M + scat_blks - 1) / scat_blks;
    const float invN = 1.0f / (float)N;

    // weight prep (also zeroes bfill — must precede bucket_scatter)
    prep_weights<<<208, 256, 0, stream>>>(W1, W2, W_res, W_fin, W1t, W2t, Wrt, Wft, bfill);

    // CSR build
    bucket_scatter<<<scat_blks, 256, 0, stream>>>(srcA, dstA, bfill, staging, E, N, chunk);
    fine_sort<<<NB, 256, 0, stream>>>(staging, bfill, row_ptr, csr, NB, N);

    // conv1: x @ W1 -> f16 hb, + fused attention coefficients (4 heads)
    mfma_gemm<128, false, 4, float><<<grid_mfma, 256, 0, stream>>>(
        x, W1t, nullptr, nullptr, att_src1, att_dst1, as1, ad1, (_Float16*)hb, N);
    gat_agg_h4<<<grid_nodes, 256, 0, stream>>>((const _Float16*)hb, as1, ad1, row_ptr, csr,
                                               bias1, nb, N);

    // BN1 (two-stage, deterministic)
    bn_part<<<256, 256, 0, stream>>>(nb, bnpart, N);
    bn_reduce<<<1, 1024, 0, stream>>>(bnpart, gamma1, beta1, scale1, shift1, invN);

    // conv2: relu(bn1(nb)) @ W2 -> f16 hb, + fused attention coefficients (1 head)
    mfma_gemm<128, true, 1, _Float16><<<grid_mfma, 256, 0, stream>>>(
        nb, W2t, scale1, shift1, att_src2, att_dst2, as2, ad2, (_Float16*)hb, N);
    gat_agg_h1<<<grid_nodes, 256, 0, stream>>>((const _Float16*)hb, as2, ad2, row_ptr, csr,
                                               bias2, nb, N);

    // BN2 (two-stage, deterministic)
    bn_part<<<256, 256, 0, stream>>>(nb, bnpart, N);
    bn_reduce<<<1, 1024, 0, stream>>>(bnpart, gamma2, beta2, scale2, shift2, invN);

    // fused: res = x@Wres+b_res (LDS); out = ((relu(bn2(nb))+res)*c) @ Wfin + b_fin
    final_fused<<<grid_mfma, 256, 0, stream>>>(x, nb, Wrt, Wft, b_res, scale2, shift2,
                                               b_fin, out, N);
}

// Round 15
// 258.555 us; speedup vs baseline: 1.1748x; 1.0124x over previous
//
#include <hip/hip_runtime.h>
#include <hip/hip_fp16.h>
#include <type_traits>

#define NEG_SLOPE 0.2f
#define INV_SQRT2 0.7071067811865476f
#define BCAP 8192   // padded per-bucket staging capacity (avg ~4337 edges/bucket)

typedef _Float16 half8 __attribute__((ext_vector_type(8)));
typedef float floatx4 __attribute__((ext_vector_type(4)));

__device__ __forceinline__ float lrelu(float x) { return x > 0.f ? x : NEG_SLOPE * x; }

// ---------------- weight prep + bfill zero (runs first, so no memset dispatch) ----------------

__global__ __launch_bounds__(256) void prep_weights(const float* __restrict__ W1,
                                                    const float* __restrict__ W2,
                                                    const float* __restrict__ Wres,
                                                    const float* __restrict__ Wfin,
                                                    _Float16* __restrict__ W1t,
                                                    _Float16* __restrict__ W2t,
                                                    _Float16* __restrict__ Wrt,
                                                    _Float16* __restrict__ Wft,
                                                    int* __restrict__ bfill) {
    if (blockIdx.x == 0) bfill[threadIdx.x] = 0;
    int i = blockIdx.x * 256 + threadIdx.x;
    if (i < 16384) {
        int k = i >> 7, n = i & 127;
        W1t[n * 136 + k] = (_Float16)W1[i];
    } else if (i < 32768) {
        int j = i - 16384; int k = j >> 7, n = j & 127;
        W2t[n * 136 + k] = (_Float16)W2[j];
    } else if (i < 49152) {
        int j = i - 32768; int k = j >> 7, n = j & 127;
        Wrt[n * 136 + k] = (_Float16)Wres[j];
    } else if (i < 53248) {
        int j = i - 49152; int k = j >> 5, n = j & 31;
        Wft[n * 136 + k] = (_Float16)Wfin[j];
    }
}

// ---------------- CSR build: two-level bucket sort by dst ----------------
// staging entry packed: src (24 bits) | (dst & 255) << 24

__device__ __forceinline__ void scatter_body(const int* __restrict__ src,
                                             const int* __restrict__ dst,
                                             int* __restrict__ bucket_fill,
                                             unsigned* __restrict__ staging,
                                             int E, int N, int chunk) {
    __shared__ int lds[256];
    int tid = threadIdx.x;
    int M = E + N;
    int begin = blockIdx.x * chunk;
    int endc = min(begin + chunk, M);
    lds[tid] = 0;
    __syncthreads();
    for (int i = begin + tid; i < endc; i += 256) {
        int d = (i < E) ? dst[i] : (i - E);
        atomicAdd(&lds[d >> 8], 1);
    }
    __syncthreads();
    int h = lds[tid];
    int base = 0;
    if (h > 0) base = atomicAdd(&bucket_fill[tid], h);
    __syncthreads();
    lds[tid] = base;
    __syncthreads();
    for (int i = begin + tid; i < endc; i += 256) {
        int s, d;
        if (i < E) { s = src[i]; d = dst[i]; } else { s = d = i - E; }
        int b = d >> 8;
        int r = atomicAdd(&lds[b], 1);
        if (r < BCAP) staging[b * BCAP + r] = (unsigned)s | ((unsigned)(d & 255) << 24);
    }
}

__global__ __launch_bounds__(256) void fine_sort(const unsigned* __restrict__ staging,
                                                 const int* __restrict__ bucket_fill,
                                                 int* __restrict__ row_ptr,
                                                 int* __restrict__ csr_src, int NB, int N) {
    __shared__ int sb[256];
    __shared__ int c1[256];
    __shared__ int s1[256];
    int t = threadIdx.x;
    int b = blockIdx.x;
    int c = (t < NB) ? min(bucket_fill[t], BCAP) : 0;
    sb[t] = c;
    __syncthreads();
    for (int off = 1; off < 256; off <<= 1) {
        int add = (t >= off) ? sb[t - off] : 0;
        __syncthreads();
        sb[t] += add;
        __syncthreads();
    }
    int hi = sb[b];
    int lo = (b > 0) ? sb[b - 1] : 0;
    int cnt = hi - lo;
    if (b == NB - 1 && t == 0) row_ptr[N] = sb[NB - 1];
    const unsigned* stg = staging + (long)b * BCAP;
    c1[t] = 0;
    __syncthreads();
    for (int k = t; k < cnt; k += 256) atomicAdd(&c1[stg[k] >> 24], 1);
    __syncthreads();
    int v = c1[t];
    s1[t] = v;
    __syncthreads();
    for (int off = 1; off < 256; off <<= 1) {
        int add = (t >= off) ? s1[t - off] : 0;
        __syncthreads();
        s1[t] += add;
        __syncthreads();
    }
    int excl = s1[t] - v;
    int node = b * 256 + t;
    if (node < N) row_ptr[node] = lo + excl;
    c1[t] = lo + excl;   // cursor
    __syncthreads();
    for (int k = t; k < cnt; k += 256) {
        unsigned e = stg[k];
        int p = atomicAdd(&c1[e >> 24], 1);
        csr_src[p] = (int)(e & 0xFFFFFFu);
    }
}

// ---------------- MFMA f16 GEMM body + fused attention coefficients ----------------
// A-layout (verified): lane supplies A[m = lane&15][k = quad*8 + j]. W staged in LDS only.
// ATTN = 0/1/4 heads: as/ad computed from fp32 accumulators in the epilogue via
// shfl_xor over offsets 1,2,4,8 (stays within the 16-lane quad-group).
// BN uses precomputed global scale/shift (bn_reduce kernel) — R13 showed inline
// partial-reduction in every GEMM block regresses.

template <int NCOLS, bool DO_BN, int ATTN, typename AT>
__device__ __forceinline__ void gemm_body(int bid, const AT* __restrict__ A,
                                          const _Float16* __restrict__ Wt,
                                          const float* __restrict__ sc_,
                                          const float* __restrict__ sh_,
                                          const float* __restrict__ a_src,
                                          const float* __restrict__ a_dst,
                                          float* __restrict__ as_out,
                                          float* __restrict__ ad_out,
                                          _Float16* __restrict__ out_h, int nrows) {
    __shared__ __align__(16) _Float16 Ws[NCOLS * 136];
    int tid = threadIdx.x;
    {
        const float4* srcp = (const float4*)Wt;
        float4* dstp = (float4*)Ws;
        for (int i = tid; i < NCOLS * 17; i += 256) dstp[i] = srcp[i];
    }
    __syncthreads();

    int wave = tid >> 6, lane = tid & 63;
    int lrow = lane & 15, quad = lane >> 4;
    int m0 = bid * 128 + wave * 32;
    long r0 = min(m0 + lrow, nrows - 1);
    long r1 = min(m0 + 16 + lrow, nrows - 1);
    constexpr int NT = NCOLS / 16;
    floatx4 acc[2][NT];
#pragma unroll
    for (int ms = 0; ms < 2; ++ms)
#pragma unroll
        for (int nt = 0; nt < NT; ++nt) acc[ms][nt] = (floatx4){0.f, 0.f, 0.f, 0.f};

#pragma unroll
    for (int ks = 0; ks < 4; ++ks) {
        int k0 = ks * 32 + quad * 8;
        float av[2][8];
        if constexpr (std::is_same<AT, float>::value) {
            float4 f0 = *(const float4*)&A[r0 * 128 + k0];
            float4 f1 = *(const float4*)&A[r0 * 128 + k0 + 4];
            av[0][0] = f0.x; av[0][1] = f0.y; av[0][2] = f0.z; av[0][3] = f0.w;
            av[0][4] = f1.x; av[0][5] = f1.y; av[0][6] = f1.z; av[0][7] = f1.w;
            float4 g0 = *(const float4*)&A[r1 * 128 + k0];
            float4 g1 = *(const float4*)&A[r1 * 128 + k0 + 4];
            av[1][0] = g0.x; av[1][1] = g0.y; av[1][2] = g0.z; av[1][3] = g0.w;
            av[1][4] = g1.x; av[1][5] = g1.y; av[1][6] = g1.z; av[1][7] = g1.w;
        } else {
            half8 h0 = *(const half8*)&A[r0 * 128 + k0];
            half8 h1 = *(const half8*)&A[r1 * 128 + k0];
#pragma unroll
            for (int u = 0; u < 8; ++u) {
                av[0][u] = (float)h0[u];
                av[1][u] = (float)h1[u];
            }
        }
        if (DO_BN) {
            float4 sc0 = *(const float4*)&sc_[k0];
            float4 sc1 = *(const float4*)&sc_[k0 + 4];
            float4 sh0 = *(const float4*)&sh_[k0];
            float4 sh1 = *(const float4*)&sh_[k0 + 4];
            float scv[8] = {sc0.x, sc0.y, sc0.z, sc0.w, sc1.x, sc1.y, sc1.z, sc1.w};
            float shv[8] = {sh0.x, sh0.y, sh0.z, sh0.w, sh1.x, sh1.y, sh1.z, sh1.w};
#pragma unroll
            for (int ms = 0; ms < 2; ++ms)
#pragma unroll
                for (int u = 0; u < 8; ++u)
                    av[ms][u] = fmaxf(av[ms][u] * scv[u] + shv[u], 0.f);
        }
        half8 a0h, a1h;
#pragma unroll
        for (int u = 0; u < 8; ++u) {
            a0h[u] = (_Float16)av[0][u];
            a1h[u] = (_Float16)av[1][u];
        }
#pragma unroll
        for (int nt = 0; nt < NT; ++nt) {
            half8 b = *(half8*)&Ws[(nt * 16 + lrow) * 136 + k0];
            acc[0][nt] = __builtin_amdgcn_mfma_f32_16x16x32_f16(a0h, b, acc[0][nt], 0, 0, 0);
            acc[1][nt] = __builtin_amdgcn_mfma_f32_16x16x32_f16(a1h, b, acc[1][nt], 0, 0, 0);
        }
    }

    // epilogue: C/D layout col=lane&15, row=quad*4+reg
#pragma unroll
    for (int ms = 0; ms < 2; ++ms) {
#pragma unroll
        for (int nt = 0; nt < NT; ++nt) {
            int col = nt * 16 + lrow;
#pragma unroll
            for (int reg = 0; reg < 4; ++reg) {
                int r = m0 + ms * 16 + quad * 4 + reg;
                if (r < nrows) out_h[(long)r * NCOLS + col] = (_Float16)acc[ms][nt][reg];
            }
        }
    }

    if constexpr (ATTN > 0) {
        float asrc_l[NT], adst_l[NT];
#pragma unroll
        for (int nt = 0; nt < NT; ++nt) {
            asrc_l[nt] = a_src[nt * 16 + lrow];
            adst_l[nt] = a_dst[nt * 16 + lrow];
        }
#pragma unroll
        for (int ms = 0; ms < 2; ++ms) {
#pragma unroll
            for (int reg = 0; reg < 4; ++reg) {
                int r = m0 + ms * 16 + quad * 4 + reg;
                if constexpr (ATTN == 4) {
                    // head h owns cols [32h, 32h+32) = nt 2h, 2h+1
                    float ps[4], pd[4];
#pragma unroll
                    for (int h = 0; h < 4; ++h) {
                        ps[h] = acc[ms][2 * h][reg] * asrc_l[2 * h] +
                                acc[ms][2 * h + 1][reg] * asrc_l[2 * h + 1];
                        pd[h] = acc[ms][2 * h][reg] * adst_l[2 * h] +
                                acc[ms][2 * h + 1][reg] * adst_l[2 * h + 1];
                    }
#pragma unroll
                    for (int off = 1; off < 16; off <<= 1) {
#pragma unroll
                        for (int h = 0; h < 4; ++h) {
                            ps[h] += __shfl_xor(ps[h], off);
                            pd[h] += __shfl_xor(pd[h], off);
                        }
                    }
                    if (r < nrows && lrow < 4) {
                        float psv = lrow == 0 ? ps[0] : lrow == 1 ? ps[1]
                                  : lrow == 2 ? ps[2] : ps[3];
                        float pdv = lrow == 0 ? pd[0] : lrow == 1 ? pd[1]
                                  : lrow == 2 ? pd[2] : pd[3];
                        as_out[r * 4 + lrow] = psv;
                        ad_out[r * 4 + lrow] = pdv;
                    }
                } else {
                    float ps = 0.f, pd = 0.f;
#pragma unroll
                    for (int nt = 0; nt < NT; ++nt) {
                        ps += acc[ms][nt][reg] * asrc_l[nt];
                        pd += acc[ms][nt][reg] * adst_l[nt];
                    }
#pragma unroll
                    for (int off = 1; off < 16; off <<= 1) {
                        ps += __shfl_xor(ps, off);
                        pd += __shfl_xor(pd, off);
                    }
                    if (r < nrows && lrow == 0) {
                        as_out[r] = ps;
                        ad_out[r] = pd;
                    }
                }
            }
        }
    }
}

// ---------------- fused bucket_scatter + conv1 (independent work, one dispatch) ----------------
// Blocks [0, scat_blks): edge scatter (memory/atomic-bound).
// Blocks [scat_blks, ...): conv1 GEMM + 4-head attention (MFMA-bound). Disjoint pipes overlap.

__global__ __launch_bounds__(256) void scatter_conv1(const int* __restrict__ src,
                                                     const int* __restrict__ dst,
                                                     int* __restrict__ bucket_fill,
                                                     unsigned* __restrict__ staging,
                                                     int E, int Nn, int chunk, int scat_blks,
                                                     const float* __restrict__ x,
                                                     const _Float16* __restrict__ W1t,
                                                     const float* __restrict__ a_src,
                                                     const float* __restrict__ a_dst,
                                                     float* __restrict__ as_out,
                                                     float* __restrict__ ad_out,
                                                     _Float16* __restrict__ out_h, int nrows) {
    if ((int)blockIdx.x < scat_blks) {
        scatter_body(src, dst, bucket_fill, staging, E, Nn, chunk);
    } else {
        gemm_body<128, false, 4, float>(blockIdx.x - scat_blks, x, W1t, nullptr, nullptr,
                                        a_src, a_dst, as_out, ad_out, out_h, nrows);
    }
}

// conv2 wrapper: BN1 scale/shift (precomputed) + 1-head attention
__global__ __launch_bounds__(256) void conv2_kernel(const _Float16* __restrict__ A,
                                                    const _Float16* __restrict__ Wt,
                                                    const float* __restrict__ sc_,
                                                    const float* __restrict__ sh_,
                                                    const float* __restrict__ a_src,
                                                    const float* __restrict__ a_dst,
                                                    float* __restrict__ as_out,
                                                    float* __restrict__ ad_out,
                                                    _Float16* __restrict__ out_h, int nrows) {
    gemm_body<128, true, 1, _Float16>(blockIdx.x, A, Wt, sc_, sh_, a_src, a_dst,
                                      as_out, ad_out, out_h, nrows);
}

// ---------------- fused residual + final GEMM ----------------
// Phase 1: res = x @ Wres + b_res for this block's 128 rows -> LDS tile (f16).
// Phase 2: out = ((relu(bn2(nb)) + res) * INV_SQRT2) @ Wfin + b_fin (fp32 out).

__global__ __launch_bounds__(256) void final_fused(const float* __restrict__ x,
                                                   const _Float16* __restrict__ nb,
                                                   const _Float16* __restrict__ Wrt,
                                                   const _Float16* __restrict__ Wft,
                                                   const float* __restrict__ b_res,
                                                   const float* __restrict__ sc_,
                                                   const float* __restrict__ sh_,
                                                   const float* __restrict__ b_fin,
                                                   float* __restrict__ out, int nrows) {
    __shared__ __align__(16) _Float16 Wr[128 * 136];   // 34 KB
    __shared__ __align__(16) _Float16 Wf[32 * 136];    // 8.5 KB
    __shared__ __align__(16) _Float16 Rt[128 * 136];   // 34 KB res tile
    int tid = threadIdx.x;
    {
        const float4* srcp = (const float4*)Wrt;
        float4* dstp = (float4*)Wr;
        for (int i = tid; i < 128 * 17; i += 256) dstp[i] = srcp[i];
        const float4* srcf = (const float4*)Wft;
        float4* dstf = (float4*)Wf;
        for (int i = tid; i < 32 * 17; i += 256) dstf[i] = srcf[i];
    }
    __syncthreads();

    int wave = tid >> 6, lane = tid & 63;
    int lrow = lane & 15, quad = lane >> 4;
    int m0 = blockIdx.x * 128 + wave * 32;
    long r0 = min(m0 + lrow, nrows - 1);
    long r1 = min(m0 + 16 + lrow, nrows - 1);

    // ---- phase 1: res GEMM (fp32 A from x) ----
    floatx4 acc[2][8];
#pragma unroll
    for (int ms = 0; ms < 2; ++ms)
#pragma unroll
        for (int nt = 0; nt < 8; ++nt) acc[ms][nt] = (floatx4){0.f, 0.f, 0.f, 0.f};
#pragma unroll
    for (int ks = 0; ks < 4; ++ks) {
        int k0 = ks * 32 + quad * 8;
        half8 a0h, a1h;
        {
            float4 f0 = *(const float4*)&x[r0 * 128 + k0];
            float4 f1 = *(const float4*)&x[r0 * 128 + k0 + 4];
            float4 g0 = *(const float4*)&x[r1 * 128 + k0];
            float4 g1 = *(const float4*)&x[r1 * 128 + k0 + 4];
            a0h[0] = (_Float16)f0.x; a0h[1] = (_Float16)f0.y;
            a0h[2] = (_Float16)f0.z; a0h[3] = (_Float16)f0.w;
            a0h[4] = (_Float16)f1.x; a0h[5] = (_Float16)f1.y;
            a0h[6] = (_Float16)f1.z; a0h[7] = (_Float16)f1.w;
            a1h[0] = (_Float16)g0.x; a1h[1] = (_Float16)g0.y;
            a1h[2] = (_Float16)g0.z; a1h[3] = (_Float16)g0.w;
            a1h[4] = (_Float16)g1.x; a1h[5] = (_Float16)g1.y;
            a1h[6] = (_Float16)g1.z; a1h[7] = (_Float16)g1.w;
        }
#pragma unroll
        for (int nt = 0; nt < 8; ++nt) {
            half8 b = *(half8*)&Wr[(nt * 16 + lrow) * 136 + k0];
            acc[0][nt] = __builtin_amdgcn_mfma_f32_16x16x32_f16(a0h, b, acc[0][nt], 0, 0, 0);
            acc[1][nt] = __builtin_amdgcn_mfma_f32_16x16x32_f16(a1h, b, acc[1][nt], 0, 0, 0);
        }
    }
#pragma unroll
    for (int ms = 0; ms < 2; ++ms) {
#pragma unroll
        for (int nt = 0; nt < 8; ++nt) {
            int col = nt * 16 + lrow;
            float bv = b_res[col];
#pragma unroll
            for (int reg = 0; reg < 4; ++reg) {
                int lr = wave * 32 + ms * 16 + quad * 4 + reg;
                Rt[lr * 136 + col] = (_Float16)(acc[ms][nt][reg] + bv);
            }
        }
    }
    __syncthreads();

    // ---- phase 2: final GEMM (A = (relu(bn2(nb)) + res) * inv_sqrt2) ----
    floatx4 fac[2][2];
#pragma unroll
    for (int ms = 0; ms < 2; ++ms)
#pragma unroll
        for (int nt = 0; nt < 2; ++nt) fac[ms][nt] = (floatx4){0.f, 0.f, 0.f, 0.f};
#pragma unroll
    for (int ks = 0; ks < 4; ++ks) {
        int k0 = ks * 32 + quad * 8;
        float4 sc0 = *(const float4*)&sc_[k0];
        float4 sc1 = *(const float4*)&sc_[k0 + 4];
        float4 sh0 = *(const float4*)&sh_[k0];
        float4 sh1 = *(const float4*)&sh_[k0 + 4];
        float scv[8] = {sc0.x, sc0.y, sc0.z, sc0.w, sc1.x, sc1.y, sc1.z, sc1.w};
        float shv[8] = {sh0.x, sh0.y, sh0.z, sh0.w, sh1.x, sh1.y, sh1.z, sh1.w};
        half8 n0 = *(const half8*)&nb[r0 * 128 + k0];
        half8 n1 = *(const half8*)&nb[r1 * 128 + k0];
        int lr0 = wave * 32 + lrow;
        int lr1 = wave * 32 + 16 + lrow;
        half8 e0 = *(const half8*)&Rt[lr0 * 136 + k0];
        half8 e1 = *(const half8*)&Rt[lr1 * 136 + k0];
        half8 a0h, a1h;
#pragma unroll
        for (int u = 0; u < 8; ++u) {
            float v0 = fmaxf((float)n0[u] * scv[u] + shv[u], 0.f);
            float v1 = fmaxf((float)n1[u] * scv[u] + shv[u], 0.f);
            a0h[u] = (_Float16)((v0 + (float)e0[u]) * INV_SQRT2);
            a1h[u] = (_Float16)((v1 + (float)e1[u]) * INV_SQRT2);
        }
#pragma unroll
        for (int nt = 0; nt < 2; ++nt) {
            half8 b = *(half8*)&Wf[(nt * 16 + lrow) * 136 + k0];
            fac[0][nt] = __builtin_amdgcn_mfma_f32_16x16x32_f16(a0h, b, fac[0][nt], 0, 0, 0);
            fac[1][nt] = __builtin_amdgcn_mfma_f32_16x16x32_f16(a1h, b, fac[1][nt], 0, 0, 0);
        }
    }
#pragma unroll
    for (int ms = 0; ms < 2; ++ms) {
#pragma unroll
        for (int nt = 0; nt < 2; ++nt) {
            int col = nt * 16 + lrow;
            float bv = b_fin[col];
#pragma unroll
            for (int reg = 0; reg < 4; ++reg) {
                int r = m0 + ms * 16 + quad * 4 + reg;
                if (r < nrows) out[(long)r * 32 + col] = fac[ms][nt][reg] + bv;
            }
        }
    }
}

// ---------------- GAT aggregation: alpha computed inline ----------------
// wave/node; group g = lane>>4 handles edges j+g+4k, k=0..3; lane covers 8 channels.
// softmax shift-invariant; logits O(3) so exp cannot overflow.

__global__ __launch_bounds__(256) void gat_agg_h4(const _Float16* __restrict__ h,
                                                  const float* __restrict__ as,
                                                  const float* __restrict__ ad,
                                                  const int* __restrict__ row_ptr,
                                                  const int* __restrict__ csr_src,
                                                  const float* __restrict__ bias,
                                                  _Float16* __restrict__ out, int n) {
    long gt = blockIdx.x * (long)blockDim.x + threadIdx.x;
    int node = (int)(gt >> 6);
    if (node >= n) return;
    int lane = threadIdx.x & 63;
    int lg = lane & 15, g = lane >> 4;
    int hh = lg >> 2;
    int start = row_ptr[node], end = row_ptr[node + 1];
    float adh = ad[node * 4 + hh];
    float acc[8] = {0, 0, 0, 0, 0, 0, 0, 0};
    float t = 0.f;
    for (int j = start; j < end; j += 16) {
        int s[4];
        float av[4];
#pragma unroll
        for (int k = 0; k < 4; ++k) {
            int je = j + g + 4 * k;
            bool vk = je < end;
            int jc = vk ? je : start;
            s[k] = csr_src[jc];
            av[k] = vk ? 1.f : 0.f;
        }
        float asv[4];
#pragma unroll
        for (int k = 0; k < 4; ++k) asv[k] = as[s[k] * 4 + hh];
        half8 hv[4];
#pragma unroll
        for (int k = 0; k < 4; ++k) hv[k] = *(const half8*)&h[(long)s[k] * 128 + lg * 8];
#pragma unroll
        for (int k = 0; k < 4; ++k) {
            float a = av[k] * __expf(lrelu(asv[k] + adh));
            t += a;
#pragma unroll
            for (int u = 0; u < 8; ++u) acc[u] += (float)hv[k][u] * a;
        }
    }
#pragma unroll
    for (int off = 16; off < 64; off <<= 1) {
        t += __shfl_xor(t, off);
#pragma unroll
        for (int u = 0; u < 8; ++u) acc[u] += __shfl_xor(acc[u], off);
    }
    if (g == 0) {
        float inv = 1.f / (t + 1e-16f);
        int cb = lg * 8;
        float4 b0 = *(const float4*)&bias[cb];
        float4 b1 = *(const float4*)&bias[cb + 4];
        half8 o;
        o[0] = (_Float16)(acc[0] * inv + b0.x);
        o[1] = (_Float16)(acc[1] * inv + b0.y);
        o[2] = (_Float16)(acc[2] * inv + b0.z);
        o[3] = (_Float16)(acc[3] * inv + b0.w);
        o[4] = (_Float16)(acc[4] * inv + b1.x);
        o[5] = (_Float16)(acc[5] * inv + b1.y);
        o[6] = (_Float16)(acc[6] * inv + b1.z);
        o[7] = (_Float16)(acc[7] * inv + b1.w);
        *(half8*)&out[(long)node * 128 + cb] = o;
    }
}

__global__ __launch_bounds__(256) void gat_agg_h1(const _Float16* __restrict__ h,
                                                  const float* __restrict__ as,
                                                  const float* __restrict__ ad,
                                                  const int* __restrict__ row_ptr,
                                                  const int* __restrict__ csr_src,
                                                  const float* __restrict__ bias,
                                                  _Float16* __restrict__ out, int n) {
    long gt = blockIdx.x * (long)blockDim.x + threadIdx.x;
    int node = (int)(gt >> 6);
    if (node >= n) return;
    int lane = threadIdx.x & 63;
    int lg = lane & 15, g = lane >> 4;
    int start = row_ptr[node], end = row_ptr[node + 1];
    float adn = ad[node];
    float acc[8] = {0, 0, 0, 0, 0, 0, 0, 0};
    float t = 0.f;
    for (int j = start; j < end; j += 16) {
        int s[4];
        float av[4];
#pragma unroll
        for (int k = 0; k < 4; ++k) {
            int je = j + g + 4 * k;
            bool vk = je < end;
            int jc = vk ? je : start;
            s[k] = csr_src[jc];
            av[k] = vk ? 1.f : 0.f;
        }
        float asv[4];
#pragma unroll
        for (int k = 0; k < 4; ++k) asv[k] = as[s[k]];
        half8 hv[4];
#pragma unroll
        for (int k = 0; k < 4; ++k) hv[k] = *(const half8*)&h[(long)s[k] * 128 + lg * 8];
#pragma unroll
        for (int k = 0; k < 4; ++k) {
            float a = av[k] * __expf(lrelu(asv[k] + adn));
            t += a;
#pragma unroll
            for (int u = 0; u < 8; ++u) acc[u] += (float)hv[k][u] * a;
        }
    }
#pragma unroll
    for (int off = 16; off < 64; off <<= 1) {
        t += __shfl_xor(t, off);
#pragma unroll
        for (int u = 0; u < 8; ++u) acc[u] += __shfl_xor(acc[u], off);
    }
    if (g == 0) {
        float inv = 1.f / (t + 1e-16f);
        int cb = lg * 8;
        float4 b0 = *(const float4*)&bias[cb];
        float4 b1 = *(const float4*)&bias[cb + 4];
        half8 o;
        o[0] = (_Float16)(acc[0] * inv + b0.x);
        o[1] = (_Float16)(acc[1] * inv + b0.y);
        o[2] = (_Float16)(acc[2] * inv + b0.z);
        o[3] = (_Float16)(acc[3] * inv + b0.w);
        o[4] = (_Float16)(acc[4] * inv + b1.x);
        o[5] = (_Float16)(acc[5] * inv + b1.y);
        o[6] = (_Float16)(acc[6] * inv + b1.z);
        o[7] = (_Float16)(acc[7] * inv + b1.w);
        *(half8*)&out[(long)node * 128 + cb] = o;
    }
}

// ---------------- BatchNorm: two-stage deterministic reduction (no atomics) ----------------
// R8/R9/R13 lessons: 256-block stage 1 (full-chip BW), 1024-thread stage 2 (TLP);
// do NOT shrink stage-1 grid or inline stage 2 into consumer GEMM blocks.

__global__ __launch_bounds__(256) void bn_part(const _Float16* __restrict__ h,
                                               float* __restrict__ partial, int n) {
    int tid = threadIdx.x;
    int lg = tid & 15;
    int rg = tid >> 4;   // 0..15
    int b = blockIdx.x;
    int chunk = (n + gridDim.x - 1) / (int)gridDim.x;
    int r0 = b * chunk;
    int r1 = min(r0 + chunk, n);
    float fs[8] = {0, 0, 0, 0, 0, 0, 0, 0};
    float fq[8] = {0, 0, 0, 0, 0, 0, 0, 0};
    for (int r = r0 + rg; r < r1; r += 16) {
        half8 hv = *(const half8*)&h[(long)r * 128 + lg * 8];
#pragma unroll
        for (int u = 0; u < 8; ++u) {
            float v = (float)hv[u];
            fs[u] += v;
            fq[u] += v * v;
        }
    }
#pragma unroll
    for (int off = 16; off < 64; off <<= 1) {
#pragma unroll
        for (int u = 0; u < 8; ++u) {
            fs[u] += __shfl_xor(fs[u], off);
            fq[u] += __shfl_xor(fq[u], off);
        }
    }
    __shared__ float reds[4][128], redq[4][128];
    int wave = tid >> 6, lane = tid & 63;
    if (lane < 16) {
#pragma unroll
        for (int u = 0; u < 8; ++u) {
            reds[wave][lane * 8 + u] = fs[u];
            redq[wave][lane * 8 + u] = fq[u];
        }
    }
    __syncthreads();
    if (tid < 128) {
        float s = reds[0][tid] + reds[1][tid] + reds[2][tid] + reds[3][tid];
        float q = redq[0][tid] + redq[1][tid] + redq[2][tid] + redq[3][tid];
        partial[b * 256 + tid] = s;
        partial[b * 256 + 128 + tid] = q;
    }
}

__global__ __launch_bounds__(1024) void bn_reduce(const float* __restrict__ partial,
                                                  const float* __restrict__ gamma,
                                                  const float* __restrict__ beta,
                                                  float* __restrict__ scale,
                                                  float* __restrict__ shift, float invN) {
    __shared__ float lds_s[8][128], lds_q[8][128];
    int c = threadIdx.x & 127;
    int sl = threadIdx.x >> 7;   // 0..7
    float s = 0.f, q = 0.f;
#pragma unroll 4
    for (int k = sl; k < 256; k += 8) {
        s += partial[k * 256 + c];
        q += partial[k * 256 + 128 + c];
    }
    lds_s[sl][c] = s;
    lds_q[sl][c] = q;
    __syncthreads();
    if (threadIdx.x < 128) {
        float S = 0.f, Q = 0.f;
#pragma unroll
        for (int i = 0; i < 8; ++i) { S += lds_s[i][c]; Q += lds_q[i][c]; }
        float mean = S * invN;
        float var = Q * invN - mean * mean;
        float sc = gamma[c] * rsqrtf(var + 1e-5f);
        scale[c] = sc;
        shift[c] = beta[c] - mean * sc;
    }
}

// ---------------- launch ----------------

extern "C" void kernel_launch(void* const* d_in, const int* in_sizes, int n_in,
                              void* d_out, int out_size, void* d_ws, size_t ws_size,
                              hipStream_t stream) {
    const float* x        = (const float*)d_in[0];
    const int*   ei       = (const int*)d_in[1];
    const float* W1       = (const float*)d_in[2];
    const float* att_src1 = (const float*)d_in[3];
    const float* att_dst1 = (const float*)d_in[4];
    const float* bias1    = (const float*)d_in[5];
    const float* W2       = (const float*)d_in[6];
    const float* att_src2 = (const float*)d_in[7];
    const float* att_dst2 = (const float*)d_in[8];
    const float* bias2    = (const float*)d_in[9];
    const float* gamma1   = (const float*)d_in[10];
    const float* beta1    = (const float*)d_in[11];
    const float* gamma2   = (const float*)d_in[12];
    const float* beta2    = (const float*)d_in[13];
    const float* W_res    = (const float*)d_in[14];
    const float* b_res    = (const float*)d_in[15];
    const float* W_fin    = (const float*)d_in[16];
    const float* b_fin    = (const float*)d_in[17];
    float* out = (float*)d_out;

    const int N = in_sizes[0] / 128;
    const int E = in_sizes[1] / 2;
    const int M = E + N;
    const int NB = (N + 255) >> 8;   // 196 coarse buckets
    const int* srcA = ei;
    const int* dstA = ei + E;

    char* w = (char*)d_ws;
    size_t off = 0;
    auto alloc = [&](size_t bytes) -> void* {
        off = (off + 255) & ~(size_t)255;
        void* p = w + off;
        off += bytes;
        return p;
    };
    __half*    hb      = (__half*)alloc((size_t)N * 128 * 2);        // conv outputs
    _Float16*  nb      = (_Float16*)alloc((size_t)N * 128 * 2);      // agg outputs (both layers)
    unsigned*  staging = (unsigned*)alloc((size_t)NB * BCAP * 4);    // packed 4B/entry
    int*       csr     = (int*)alloc((size_t)M * 4);
    int*       row_ptr = (int*)alloc((size_t)(N + 1) * 4);
    int*       bfill   = (int*)alloc((size_t)256 * 4);
    float*     bnpart  = (float*)alloc((size_t)256 * 256 * 4);
    float*     as1     = (float*)alloc((size_t)N * 4 * 4);
    float*     ad1     = (float*)alloc((size_t)N * 4 * 4);
    float*     as2     = (float*)alloc((size_t)N * 4);
    float*     ad2     = (float*)alloc((size_t)N * 4);
    _Float16*  W1t     = (_Float16*)alloc((size_t)128 * 136 * 2);
    _Float16*  W2t     = (_Float16*)alloc((size_t)128 * 136 * 2);
    _Float16*  Wrt     = (_Float16*)alloc((size_t)128 * 136 * 2);
    _Float16*  Wft     = (_Float16*)alloc((size_t)32 * 136 * 2);
    float*     scale1  = (float*)alloc(128 * 4);
    float*     shift1  = (float*)alloc(128 * 4);
    float*     scale2  = (float*)alloc(128 * 4);
    float*     shift2  = (float*)alloc(128 * 4);

    const int grid_mfma  = (N + 127) / 128;
    const int grid_nodes = (N + 3) / 4;
    const int scat_blks  = 256;
    const int chunk      = (M + scat_blks - 1) / scat_blks;
    const float invN = 1.0f / (float)N;

    // weight prep (also zeroes bfill — must precede scatter_conv1)
    prep_weights<<<208, 256, 0, stream>>>(W1, W2, W_res, W_fin, W1t, W2t, Wrt, Wft, bfill);

    // bucket_scatter + conv1 (+fused 4-head attention) in one dispatch (independent work)
    scatter_conv1<<<scat_blks + grid_mfma, 256, 0, stream>>>(
        srcA, dstA, bfill, staging, E, N, chunk, scat_blks,
        x, W1t, att_src1, att_dst1, as1, ad1, (_Float16*)hb, N);

    fine_sort<<<NB, 256, 0, stream>>>(staging, bfill, row_ptr, csr, NB, N);

    gat_agg_h4<<<grid_nodes, 256, 0, stream>>>((const _Float16*)hb, as1, ad1, row_ptr, csr,
                                               bias1, nb, N);

    // BN1 (two-stage, deterministic)
    bn_part<<<256, 256, 0, stream>>>(nb, bnpart, N);
    bn_reduce<<<1, 1024, 0, stream>>>(bnpart, gamma1, beta1, scale1, shift1, invN);

    // conv2: relu(bn1(nb)) @ W2 (+fused 1-head attention)
    conv2_kernel<<<grid_mfma, 256, 0, stream>>>(nb, W2t, scale1, shift1,
                                                att_src2, att_dst2, as2, ad2,
                                                (_Float16*)hb, N);

    gat_agg_h1<<<grid_nodes, 256, 0, stream>>>((const _Float16*)hb, as2, ad2, row_ptr, csr,
                                               bias2, nb, N);

    // BN2 (two-stage, deterministic)
    bn_part<<<256, 256, 0, stream>>>(nb, bnpart, N);
    bn_reduce<<<1, 1024, 0, stream>>>(bnpart, gamma2, beta2, scale2, shift2, invN);

    // fused: res = x@Wres+b_res (LDS); out = ((relu(bn2(nb))+res)*c) @ Wfin + b_fin
    final_fused<<<grid_mfma, 256, 0, stream>>>(x, nb, Wrt, Wft, b_res, scale2, shift2,
                                               b_fin, out, N);
}